// Round 3
// baseline (1225.159 us; speedup 1.0000x reference)
//
#include <hip/hip_runtime.h>

#define S_LEN 4096
#define EMB   1024
#define NH    16
#define HD    64
#define GH    8
#define WIN   256

// p * v16 fma into dst[0..15]
#define FMA16(pscal, v0_, v1_, v2_, v3_, dst)                         \
    dst[0]  = fmaf(pscal, v0_.x, dst[0]);  dst[1]  = fmaf(pscal, v0_.y, dst[1]);  \
    dst[2]  = fmaf(pscal, v0_.z, dst[2]);  dst[3]  = fmaf(pscal, v0_.w, dst[3]);  \
    dst[4]  = fmaf(pscal, v1_.x, dst[4]);  dst[5]  = fmaf(pscal, v1_.y, dst[5]);  \
    dst[6]  = fmaf(pscal, v1_.z, dst[6]);  dst[7]  = fmaf(pscal, v1_.w, dst[7]);  \
    dst[8]  = fmaf(pscal, v2_.x, dst[8]);  dst[9]  = fmaf(pscal, v2_.y, dst[9]);  \
    dst[10] = fmaf(pscal, v2_.z, dst[10]); dst[11] = fmaf(pscal, v2_.w, dst[11]); \
    dst[12] = fmaf(pscal, v3_.x, dst[12]); dst[13] = fmaf(pscal, v3_.y, dst[13]); \
    dst[14] = fmaf(pscal, v3_.z, dst[14]); dst[15] = fmaf(pscal, v3_.w, dst[15]);

// ---------------- fused QKV projection: Y = X @ W^T, written as [h][s][d] ----------------
// C = A * B^T; A:[4096,1024] row-major, B(W):[1024,1024] row-major.
// 128x128x32 tile, 256 threads, 8x8 per thread, transposed LDS (pad 4 -> b128-friendly).
__global__ __launch_bounds__(256) void gemm_qkv_kernel(
    const float* __restrict__ X,
    const float* __restrict__ Wq, const float* __restrict__ Wk, const float* __restrict__ Wv,
    float* __restrict__ qo, float* __restrict__ ko, float* __restrict__ vo)
{
    __shared__ float At[32][132];
    __shared__ float Bt[32][132];

    const int z = blockIdx.z;
    const float* W = (z == 0) ? Wq : (z == 1) ? Wk : Wv;
    float* outp    = (z == 0) ? qo : (z == 1) ? ko : vo;
    const float alpha = (z == 0) ? 0.125f : 1.0f;   // q scale 1/sqrt(64)

    const int tid = threadIdx.x;
    const int bm = blockIdx.x * 128;
    const int bn = blockIdx.y * 128;
    const int tx = tid & 15, ty = tid >> 4;
    const int m0 = ty * 8, n0 = tx * 8;

    float acc[8][8];
    #pragma unroll
    for (int i = 0; i < 8; ++i)
        #pragma unroll
        for (int j = 0; j < 8; ++j) acc[i][j] = 0.f;

    for (int k0 = 0; k0 < EMB; k0 += 32) {
        float4 la[4], lb[4];
        #pragma unroll
        for (int i = 0; i < 4; ++i) {
            const int f = tid + i * 256;          // 1024 float4s: 128 rows x 8
            const int r = f >> 3, c4 = f & 7;
            la[i] = *(const float4*)(X + (size_t)(bm + r) * EMB + k0 + c4 * 4);
            lb[i] = *(const float4*)(W + (size_t)(bn + r) * EMB + k0 + c4 * 4);
        }
        __syncthreads();
        #pragma unroll
        for (int i = 0; i < 4; ++i) {
            const int f = tid + i * 256;
            const int r = f >> 3, c4 = f & 7;
            At[c4*4+0][r] = la[i].x; At[c4*4+1][r] = la[i].y;
            At[c4*4+2][r] = la[i].z; At[c4*4+3][r] = la[i].w;
            Bt[c4*4+0][r] = lb[i].x; Bt[c4*4+1][r] = lb[i].y;
            Bt[c4*4+2][r] = lb[i].z; Bt[c4*4+3][r] = lb[i].w;
        }
        __syncthreads();
        #pragma unroll
        for (int kk = 0; kk < 32; ++kk) {
            float a[8], b[8];
            *(float4*)&a[0] = *(const float4*)&At[kk][m0];
            *(float4*)&a[4] = *(const float4*)&At[kk][m0 + 4];
            *(float4*)&b[0] = *(const float4*)&Bt[kk][n0];
            *(float4*)&b[4] = *(const float4*)&Bt[kk][n0 + 4];
            #pragma unroll
            for (int i = 0; i < 8; ++i)
                #pragma unroll
                for (int j = 0; j < 8; ++j)
                    acc[i][j] = fmaf(a[i], b[j], acc[i][j]);
        }
    }
    #pragma unroll
    for (int i = 0; i < 8; ++i) {
        const int m = bm + m0 + i;
        #pragma unroll
        for (int j = 0; j < 8; ++j) {
            const int n = bn + n0 + j;
            const int h = n >> 6, d = n & 63;
            outp[((size_t)h * S_LEN + m) * HD + d] = acc[i][j] * alpha;
        }
    }
}

// ---------------- output projection: out = A @ Wo^T + bo ----------------
__global__ __launch_bounds__(256) void gemm_out_kernel(
    const float* __restrict__ A, const float* __restrict__ Wo,
    const float* __restrict__ bias, float* __restrict__ out)
{
    __shared__ float At[32][132];
    __shared__ float Bt[32][132];

    const int tid = threadIdx.x;
    const int bm = blockIdx.x * 128;
    const int bn = blockIdx.y * 128;
    const int tx = tid & 15, ty = tid >> 4;
    const int m0 = ty * 8, n0 = tx * 8;

    float acc[8][8];
    #pragma unroll
    for (int i = 0; i < 8; ++i)
        #pragma unroll
        for (int j = 0; j < 8; ++j) acc[i][j] = 0.f;

    for (int k0 = 0; k0 < EMB; k0 += 32) {
        float4 la[4], lb[4];
        #pragma unroll
        for (int i = 0; i < 4; ++i) {
            const int f = tid + i * 256;
            const int r = f >> 3, c4 = f & 7;
            la[i] = *(const float4*)(A  + (size_t)(bm + r) * EMB + k0 + c4 * 4);
            lb[i] = *(const float4*)(Wo + (size_t)(bn + r) * EMB + k0 + c4 * 4);
        }
        __syncthreads();
        #pragma unroll
        for (int i = 0; i < 4; ++i) {
            const int f = tid + i * 256;
            const int r = f >> 3, c4 = f & 7;
            At[c4*4+0][r] = la[i].x; At[c4*4+1][r] = la[i].y;
            At[c4*4+2][r] = la[i].z; At[c4*4+3][r] = la[i].w;
            Bt[c4*4+0][r] = lb[i].x; Bt[c4*4+1][r] = lb[i].y;
            Bt[c4*4+2][r] = lb[i].z; Bt[c4*4+3][r] = lb[i].w;
        }
        __syncthreads();
        #pragma unroll
        for (int kk = 0; kk < 32; ++kk) {
            float a[8], b[8];
            *(float4*)&a[0] = *(const float4*)&At[kk][m0];
            *(float4*)&a[4] = *(const float4*)&At[kk][m0 + 4];
            *(float4*)&b[0] = *(const float4*)&Bt[kk][n0];
            *(float4*)&b[4] = *(const float4*)&Bt[kk][n0 + 4];
            #pragma unroll
            for (int i = 0; i < 8; ++i)
                #pragma unroll
                for (int j = 0; j < 8; ++j)
                    acc[i][j] = fmaf(a[i], b[j], acc[i][j]);
        }
    }
    #pragma unroll
    for (int i = 0; i < 8; ++i) {
        const int m = bm + m0 + i;
        #pragma unroll
        for (int j = 0; j < 8; ++j) {
            const int n = bn + n0 + j;
            out[(size_t)m * EMB + n] = acc[i][j] + bias[n];
        }
    }
}

// ---------------- flash attention, fp32 ----------------
// grid: (64 qblocks, 16 heads), 256 threads. 64 q-rows per block, K/V tiles of 64.
__global__ __launch_bounds__(256) void attn_kernel(
    const float* __restrict__ q, const float* __restrict__ k, const float* __restrict__ v,
    float* __restrict__ attn_out /* [S][E] */)
{
    __shared__ float Qs[64][68];
    __shared__ float KT[64][68];   // KT[kd][j]
    __shared__ float Vs[64][68];   // Vs[j][d]
    __shared__ float Ps[64][68];   // scores -> probabilities
    __shared__ float mrow[64], lrow[64], arow[64];

    const int qb = 63 - blockIdx.x;          // longest (late-qb causal) blocks dispatch first
    const int h  = blockIdx.y;
    const bool is_local = (h >= GH);
    const int tid = threadIdx.x;

    const float* qh = q + (size_t)h * S_LEN * HD;
    const float* kh = k + (size_t)h * S_LEN * HD;
    const float* vh = v + (size_t)h * S_LEN * HD;

    // stage Q tile [64][64]
    #pragma unroll
    for (int i = 0; i < 4; ++i) {
        const int f = tid + i * 256;          // 64 rows x 16 float4
        const int r = f >> 4, c4 = f & 15;
        float4 t4 = *(const float4*)(qh + (size_t)(qb * 64 + r) * HD + c4 * 4);
        Qs[r][c4*4+0] = t4.x; Qs[r][c4*4+1] = t4.y;
        Qs[r][c4*4+2] = t4.z; Qs[r][c4*4+3] = t4.w;
    }
    if (tid < 64) { mrow[tid] = -1e30f; lrow[tid] = 0.f; }

    // score/softmax mapping: 4 lanes per row (same wave -> shfl reduce)
    const int sr  = tid >> 2;
    const int sp  = tid & 3;
    const int sj0 = sp * 16;
    // PV mapping: each wave covers all 64 rows once; dims by wave
    const int pr  = tid & 63;
    const int pd0 = (tid >> 6) * 16;

    float acc[16];
    #pragma unroll
    for (int i = 0; i < 16; ++i) acc[i] = 0.f;

    const int kt_lo = is_local ? ((qb - 4 > 0) ? qb - 4 : 0) : 0;

    for (int kt = kt_lo; kt <= qb; ++kt) {
        float4 lk[4], lv[4];
        #pragma unroll
        for (int i = 0; i < 4; ++i) {
            const int f = tid + i * 256;
            const int r = f >> 4, c4 = f & 15;
            lk[i] = *(const float4*)(kh + (size_t)(kt * 64 + r) * HD + c4 * 4);
            lv[i] = *(const float4*)(vh + (size_t)(kt * 64 + r) * HD + c4 * 4);
        }
        __syncthreads();                      // previous tile fully consumed
        #pragma unroll
        for (int i = 0; i < 4; ++i) {
            const int f = tid + i * 256;
            const int r = f >> 4, c4 = f & 15;
            KT[c4*4+0][r] = lk[i].x; KT[c4*4+1][r] = lk[i].y;
            KT[c4*4+2][r] = lk[i].z; KT[c4*4+3][r] = lk[i].w;
            Vs[r][c4*4+0] = lv[i].x; Vs[r][c4*4+1] = lv[i].y;
            Vs[r][c4*4+2] = lv[i].z; Vs[r][c4*4+3] = lv[i].w;
        }
        __syncthreads();

        // ---- scores: row sr, cols sj0..sj0+15 ----
        float sc[16];
        #pragma unroll
        for (int i = 0; i < 16; ++i) sc[i] = 0.f;
        #pragma unroll 4
        for (int kd4 = 0; kd4 < 16; ++kd4) {
            float4 qv = *(const float4*)&Qs[sr][kd4 * 4];
            float qa[4] = {qv.x, qv.y, qv.z, qv.w};
            #pragma unroll
            for (int u = 0; u < 4; ++u) {
                const int kd = kd4 * 4 + u;
                float4 k0v = *(const float4*)&KT[kd][sj0];
                float4 k1v = *(const float4*)&KT[kd][sj0 + 4];
                float4 k2v = *(const float4*)&KT[kd][sj0 + 8];
                float4 k3v = *(const float4*)&KT[kd][sj0 + 12];
                FMA16(qa[u], k0v, k1v, k2v, k3v, sc)
            }
        }
        const int rg = qb * 64 + sr;
        #pragma unroll
        for (int jj = 0; jj < 16; ++jj) {
            const int jg = kt * 64 + sj0 + jj;
            const bool ok = (jg <= rg) && (!is_local || (jg + WIN >= rg));
            sc[jj] = ok ? sc[jj] : -1e30f;
        }

        // ---- online softmax, in-register, 4-lane groups ----
        float mx = sc[0];
        #pragma unroll
        for (int jj = 1; jj < 16; ++jj) mx = fmaxf(mx, sc[jj]);
        mx = fmaxf(mx, __shfl_xor(mx, 1));
        mx = fmaxf(mx, __shfl_xor(mx, 2));
        const float mold = mrow[sr];
        const float mnew = fmaxf(mold, mx);
        const float al = __expf(mold - mnew);
        float sum = 0.f;
        #pragma unroll
        for (int jj = 0; jj < 16; ++jj) {
            const float p = __expf(sc[jj] - mnew);
            sc[jj] = p;
            sum += p;
        }
        sum += __shfl_xor(sum, 1);
        sum += __shfl_xor(sum, 2);
        {
            float4 p0 = {sc[0],  sc[1],  sc[2],  sc[3]};
            float4 p1 = {sc[4],  sc[5],  sc[6],  sc[7]};
            float4 p2 = {sc[8],  sc[9],  sc[10], sc[11]};
            float4 p3 = {sc[12], sc[13], sc[14], sc[15]};
            *(float4*)&Ps[sr][sj0]      = p0;
            *(float4*)&Ps[sr][sj0 + 4]  = p1;
            *(float4*)&Ps[sr][sj0 + 8]  = p2;
            *(float4*)&Ps[sr][sj0 + 12] = p3;
        }
        if (sp == 0) {
            mrow[sr] = mnew;
            lrow[sr] = lrow[sr] * al + sum;
            arow[sr] = al;
        }
        __syncthreads();

        // ---- PV: row pr, dims pd0..pd0+15 ----
        const float a2 = arow[pr];
        #pragma unroll
        for (int i = 0; i < 16; ++i) acc[i] *= a2;
        #pragma unroll 8
        for (int j = 0; j < 64; ++j) {
            const float p = Ps[pr][j];
            float4 v0 = *(const float4*)&Vs[j][pd0];
            float4 v1 = *(const float4*)&Vs[j][pd0 + 4];
            float4 v2 = *(const float4*)&Vs[j][pd0 + 8];
            float4 v3 = *(const float4*)&Vs[j][pd0 + 12];
            FMA16(p, v0, v1, v2, v3, acc)
        }
        // no barrier here: next iteration's first __syncthreads (after global
        // loads) orders PV reads before KT/Vs overwrite; Ps rewrite is two
        // barriers away.
    }

    const float linv = 1.0f / lrow[pr];
    const int rg2 = qb * 64 + pr;
    float* op = attn_out + (size_t)rg2 * EMB + h * HD + pd0;
    float4 o0 = {acc[0]*linv,  acc[1]*linv,  acc[2]*linv,  acc[3]*linv};
    float4 o1 = {acc[4]*linv,  acc[5]*linv,  acc[6]*linv,  acc[7]*linv};
    float4 o2 = {acc[8]*linv,  acc[9]*linv,  acc[10]*linv, acc[11]*linv};
    float4 o3 = {acc[12]*linv, acc[13]*linv, acc[14]*linv, acc[15]*linv};
    *(float4*)(op)      = o0;
    *(float4*)(op + 4)  = o1;
    *(float4*)(op + 8)  = o2;
    *(float4*)(op + 12) = o3;
}

extern "C" void kernel_launch(void* const* d_in, const int* in_sizes, int n_in,
                              void* d_out, int out_size, void* d_ws, size_t ws_size,
                              hipStream_t stream) {
    const float* X  = (const float*)d_in[0];
    const float* Wq = (const float*)d_in[1];
    const float* Wk = (const float*)d_in[2];
    const float* Wv = (const float*)d_in[3];
    const float* Wo = (const float*)d_in[4];
    const float* bo = (const float*)d_in[5];
    float* out = (float*)d_out;

    float* ws = (float*)d_ws;
    const size_t HSD = (size_t)NH * S_LEN * HD;     // 4,194,304 floats
    float* qb  = ws;
    float* kb  = ws + HSD;
    float* vb  = ws + 2 * HSD;
    float* ab  = ws + 3 * HSD;                      // attn output [S][E]

    gemm_qkv_kernel<<<dim3(32, 8, 3), 256, 0, stream>>>(X, Wq, Wk, Wv, qb, kb, vb);
    attn_kernel<<<dim3(64, 16), 256, 0, stream>>>(qb, kb, vb, ab);
    gemm_out_kernel<<<dim3(32, 8), 256, 0, stream>>>(ab, Wo, bo, out);
}

// Round 4
// 605.492 us; speedup vs baseline: 2.0234x; 2.0234x over previous
//
#include <hip/hip_runtime.h>
#include <hip/hip_fp16.h>

#define S_LEN 4096
#define EMB   1024
#define NH    16
#define HD    64
#define GH    8
#define WIN   256

typedef _Float16 half8 __attribute__((ext_vector_type(8)));
typedef float    f32x4 __attribute__((ext_vector_type(4)));
typedef unsigned short ushort8 __attribute__((ext_vector_type(8)));

static __device__ __forceinline__ f32x4 mfma16(half8 a, half8 b, f32x4 c) {
    return __builtin_amdgcn_mfma_f32_16x16x32_f16(a, b, c, 0, 0, 0);
}

// ---------------- fused QKV projection: Y = X @ W^T, fp32 compute, fp16 out [h][s][d] ----
__global__ __launch_bounds__(256) void gemm_qkv_kernel(
    const float* __restrict__ X,
    const float* __restrict__ Wq, const float* __restrict__ Wk, const float* __restrict__ Wv,
    __half* __restrict__ qo, __half* __restrict__ ko, __half* __restrict__ vo)
{
    __shared__ float At[32][132];
    __shared__ float Bt[32][132];

    const int z = blockIdx.z;
    const float* W = (z == 0) ? Wq : (z == 1) ? Wk : Wv;
    __half* outp   = (z == 0) ? qo : (z == 1) ? ko : vo;
    const float alpha = (z == 0) ? 0.125f : 1.0f;   // q scale 1/sqrt(64)

    const int tid = threadIdx.x;
    const int bm = blockIdx.x * 128;
    const int bn = blockIdx.y * 128;
    const int tx = tid & 15, ty = tid >> 4;
    const int m0 = ty * 8, n0 = tx * 8;

    float acc[8][8];
    #pragma unroll
    for (int i = 0; i < 8; ++i)
        #pragma unroll
        for (int j = 0; j < 8; ++j) acc[i][j] = 0.f;

    for (int k0 = 0; k0 < EMB; k0 += 32) {
        float4 la[4], lb[4];
        #pragma unroll
        for (int i = 0; i < 4; ++i) {
            const int f = tid + i * 256;
            const int r = f >> 3, c4 = f & 7;
            la[i] = *(const float4*)(X + (size_t)(bm + r) * EMB + k0 + c4 * 4);
            lb[i] = *(const float4*)(W + (size_t)(bn + r) * EMB + k0 + c4 * 4);
        }
        __syncthreads();
        #pragma unroll
        for (int i = 0; i < 4; ++i) {
            const int f = tid + i * 256;
            const int r = f >> 3, c4 = f & 7;
            At[c4*4+0][r] = la[i].x; At[c4*4+1][r] = la[i].y;
            At[c4*4+2][r] = la[i].z; At[c4*4+3][r] = la[i].w;
            Bt[c4*4+0][r] = lb[i].x; Bt[c4*4+1][r] = lb[i].y;
            Bt[c4*4+2][r] = lb[i].z; Bt[c4*4+3][r] = lb[i].w;
        }
        __syncthreads();
        #pragma unroll
        for (int kk = 0; kk < 32; ++kk) {
            float a[8], b[8];
            *(float4*)&a[0] = *(const float4*)&At[kk][m0];
            *(float4*)&a[4] = *(const float4*)&At[kk][m0 + 4];
            *(float4*)&b[0] = *(const float4*)&Bt[kk][n0];
            *(float4*)&b[4] = *(const float4*)&Bt[kk][n0 + 4];
            #pragma unroll
            for (int i = 0; i < 8; ++i)
                #pragma unroll
                for (int j = 0; j < 8; ++j)
                    acc[i][j] = fmaf(a[i], b[j], acc[i][j]);
        }
    }
    const int n = bn + n0;
    const int h = n >> 6, d0 = n & 63;
    #pragma unroll
    for (int i = 0; i < 8; ++i) {
        const int m = bm + m0 + i;
        ushort8 pk;
        #pragma unroll
        for (int j = 0; j < 8; ++j)
            pk[j] = __half_as_ushort(__float2half_rn(acc[i][j] * alpha));
        *(ushort8*)(outp + ((size_t)h * S_LEN + m) * HD + d0) = pk;
    }
}

// ---------------- output projection: out = A @ Wo^T + bo (fp32, unchanged) ----------------
__global__ __launch_bounds__(256) void gemm_out_kernel(
    const float* __restrict__ A, const float* __restrict__ Wo,
    const float* __restrict__ bias, float* __restrict__ out)
{
    __shared__ float At[32][132];
    __shared__ float Bt[32][132];

    const int tid = threadIdx.x;
    const int bm = blockIdx.x * 128;
    const int bn = blockIdx.y * 128;
    const int tx = tid & 15, ty = tid >> 4;
    const int m0 = ty * 8, n0 = tx * 8;

    float acc[8][8];
    #pragma unroll
    for (int i = 0; i < 8; ++i)
        #pragma unroll
        for (int j = 0; j < 8; ++j) acc[i][j] = 0.f;

    for (int k0 = 0; k0 < EMB; k0 += 32) {
        float4 la[4], lb[4];
        #pragma unroll
        for (int i = 0; i < 4; ++i) {
            const int f = tid + i * 256;
            const int r = f >> 3, c4 = f & 7;
            la[i] = *(const float4*)(A  + (size_t)(bm + r) * EMB + k0 + c4 * 4);
            lb[i] = *(const float4*)(Wo + (size_t)(bn + r) * EMB + k0 + c4 * 4);
        }
        __syncthreads();
        #pragma unroll
        for (int i = 0; i < 4; ++i) {
            const int f = tid + i * 256;
            const int r = f >> 3, c4 = f & 7;
            At[c4*4+0][r] = la[i].x; At[c4*4+1][r] = la[i].y;
            At[c4*4+2][r] = la[i].z; At[c4*4+3][r] = la[i].w;
            Bt[c4*4+0][r] = lb[i].x; Bt[c4*4+1][r] = lb[i].y;
            Bt[c4*4+2][r] = lb[i].z; Bt[c4*4+3][r] = lb[i].w;
        }
        __syncthreads();
        #pragma unroll
        for (int kk = 0; kk < 32; ++kk) {
            float a[8], b[8];
            *(float4*)&a[0] = *(const float4*)&At[kk][m0];
            *(float4*)&a[4] = *(const float4*)&At[kk][m0 + 4];
            *(float4*)&b[0] = *(const float4*)&Bt[kk][n0];
            *(float4*)&b[4] = *(const float4*)&Bt[kk][n0 + 4];
            #pragma unroll
            for (int i = 0; i < 8; ++i)
                #pragma unroll
                for (int j = 0; j < 8; ++j)
                    acc[i][j] = fmaf(a[i], b[j], acc[i][j]);
        }
    }
    #pragma unroll
    for (int i = 0; i < 8; ++i) {
        const int m = bm + m0 + i;
        #pragma unroll
        for (int j = 0; j < 8; ++j) {
            const int n = bn + n0 + j;
            out[(size_t)m * EMB + n] = acc[i][j] + bias[n];
        }
    }
}

// ---------------- flash attention, fp16 MFMA (swapped QK^T) ----------------
// grid (64 qblocks, 16 heads), 256 threads = 4 waves; wave w owns q rows [16w,16w+16).
// LDS (all fp16, 128 B rows, XOR-swizzled byte ^= (row&7)<<4):
//   Qs[64 q][64 d], Ks[64 key][64 d], Vt[64 d][64 j], Pl per-wave [16 q][64 j].
__global__ __launch_bounds__(256) void attn_mfma_kernel(
    const __half* __restrict__ q, const __half* __restrict__ k, const __half* __restrict__ v,
    float* __restrict__ attn_out /* [S][E] fp32 */)
{
    __shared__ __align__(16) unsigned char smem[32768];
    char* Qs = (char*)smem;            // 8 KB
    char* Ks = (char*)smem + 8192;     // 8 KB
    char* Vt = (char*)smem + 16384;    // 8 KB
    char* Pl = (char*)smem + 24576;    // 8 KB (2 KB per wave)

    const int qb  = 63 - blockIdx.x;           // long causal blocks first
    const int h   = blockIdx.y;
    const bool is_local = (h >= GH);
    const int tid  = threadIdx.x;
    const int w    = tid >> 6;
    const int lane = tid & 63;
    const int lq   = lane & 15;                // q column / A row index
    const int hi   = lane >> 4;                // k-block index

    const char* qh = (const char*)(q + (size_t)h * S_LEN * HD);
    const char* kh = (const char*)(k + (size_t)h * S_LEN * HD);
    const char* vh = (const char*)(v + (size_t)h * S_LEN * HD);

    // ---- stage Q tile (pre-swizzled global source, linear LDS write) ----
    #pragma unroll
    for (int e = 0; e < 2; ++e) {
        const int flat = e * 4096 + tid * 16;
        const int row  = flat >> 7;
        const int src  = flat ^ ((row & 7) << 4);
        *(uint4*)(Qs + flat) = *(const uint4*)(qh + (size_t)qb * 8192 + src);
    }
    __syncthreads();

    // ---- Q B-frags in registers (reused across all KV tiles) ----
    half8 qf[2];
    #pragma unroll
    for (int ks = 0; ks < 2; ++ks) {
        const int row = w * 16 + lq;
        int byte = row * 128 + hi * 16 + ks * 64;
        byte ^= (row & 7) << 4;
        qf[ks] = *(const half8*)(Qs + byte);
    }

    float m_run = -1e30f, l_run = 0.f;
    f32x4 po[4];
    #pragma unroll
    for (int i = 0; i < 4; ++i) po[i] = (f32x4){0.f, 0.f, 0.f, 0.f};

    const int qg = qb * 64 + w * 16 + lq;      // this lane's global q row
    const int kt_lo = is_local ? ((qb - 4 > 0) ? qb - 4 : 0) : 0;
    char* plw = Pl + w * 2048;

    for (int kv = kt_lo; kv <= qb; ++kv) {
        __syncthreads();                       // prior tile fully consumed

        // stage K (pre-swizzled source, linear LDS write)
        #pragma unroll
        for (int e = 0; e < 2; ++e) {
            const int flat = e * 4096 + tid * 16;
            const int row  = flat >> 7;
            const int src  = flat ^ ((row & 7) << 4);
            *(uint4*)(Ks + flat) = *(const uint4*)(kh + (size_t)kv * 8192 + src);
        }
        // stage V transposed: Vt[d][j] (swizzled writes, b32 = 2 j's per store)
        {
            const int j0 = (tid & 31) * 2;
            const int d0 = (tid >> 5) * 8;
            ushort8 v0 = *(const ushort8*)(vh + (size_t)(kv * 64 + j0)     * 128 + d0 * 2);
            ushort8 v1 = *(const ushort8*)(vh + (size_t)(kv * 64 + j0 + 1) * 128 + d0 * 2);
            #pragma unroll
            for (int i = 0; i < 8; ++i) {
                const int d = d0 + i;
                int byte = d * 128 + j0 * 2;
                byte ^= (d & 7) << 4;
                *(unsigned int*)(Vt + byte) = (unsigned int)v0[i] | ((unsigned int)v1[i] << 16);
            }
        }
        __syncthreads();

        // ---- S^T = K @ Q^T : lane holds S^T[key=16kt+4hi+r][q=lq] ----
        f32x4 st[4];
        #pragma unroll
        for (int i = 0; i < 4; ++i) st[i] = (f32x4){0.f, 0.f, 0.f, 0.f};
        #pragma unroll
        for (int ks = 0; ks < 2; ++ks) {
            #pragma unroll
            for (int kt = 0; kt < 4; ++kt) {
                const int row = kt * 16 + lq;
                int byte = row * 128 + hi * 16 + ks * 64;
                byte ^= (row & 7) << 4;
                half8 kf = *(const half8*)(Ks + byte);
                st[kt] = mfma16(kf, qf[ks], st[kt]);
            }
        }

        // ---- mask + online softmax (reduce over keys: 16 in-reg + shfl 16,32) ----
        float mx = -1e30f;
        #pragma unroll
        for (int kt = 0; kt < 4; ++kt)
            #pragma unroll
            for (int r = 0; r < 4; ++r) {
                const int kg = kv * 64 + kt * 16 + hi * 4 + r;
                const bool ok = (kg <= qg) && (!is_local || (kg + WIN >= qg));
                const float s = ok ? st[kt][r] : -1e30f;
                st[kt][r] = s;
                mx = fmaxf(mx, s);
            }
        mx = fmaxf(mx, __shfl_xor(mx, 16));
        mx = fmaxf(mx, __shfl_xor(mx, 32));
        const float mnew  = fmaxf(m_run, mx);
        const float scale = __expf(m_run - mnew);
        float lsum = 0.f;
        #pragma unroll
        for (int kt = 0; kt < 4; ++kt)
            #pragma unroll
            for (int r = 0; r < 4; ++r) {
                const float p = __expf(st[kt][r] - mnew);
                st[kt][r] = p;
                lsum += p;
            }
        lsum += __shfl_xor(lsum, 16);
        lsum += __shfl_xor(lsum, 32);
        l_run = l_run * scale + lsum;
        m_run = mnew;
        #pragma unroll
        for (int dt = 0; dt < 4; ++dt)
            #pragma unroll
            for (int r = 0; r < 4; ++r) po[dt][r] *= scale;

        // ---- P -> fp16 into Pl[q][j] (wave-private, swizzled, b64 stores) ----
        #pragma unroll
        for (int kt = 0; kt < 4; ++kt) {
            int byte = lq * 128 + kt * 32 + hi * 8;
            byte ^= (lq & 7) << 4;
            union { __half2 h2[2]; uint2 u; } pu;
            pu.h2[0] = __floats2half2_rn(st[kt][0], st[kt][1]);
            pu.h2[1] = __floats2half2_rn(st[kt][2], st[kt][3]);
            *(uint2*)(plw + byte) = pu.u;
        }

        // ---- O^T += V^T @ P^T ----
        #pragma unroll
        for (int ks = 0; ks < 2; ++ks) {
            int pbyte = lq * 128 + ks * 64 + hi * 16;
            pbyte ^= (lq & 7) << 4;
            half8 pf = *(const half8*)(plw + pbyte);
            #pragma unroll
            for (int dt = 0; dt < 4; ++dt) {
                const int drow = dt * 16 + lq;
                int vbyte = drow * 128 + ks * 64 + hi * 16;
                vbyte ^= (drow & 7) << 4;
                half8 vf = *(const half8*)(Vt + vbyte);
                po[dt] = mfma16(vf, pf, po[dt]);
            }
        }
    }

    // ---- epilogue: O[q][d] = O^T / l ----
    const float linv = 1.0f / l_run;
    float* op = attn_out + (size_t)qg * EMB + h * HD;
    #pragma unroll
    for (int dt = 0; dt < 4; ++dt)
        #pragma unroll
        for (int r = 0; r < 4; ++r)
            op[dt * 16 + hi * 4 + r] = po[dt][r] * linv;
}

extern "C" void kernel_launch(void* const* d_in, const int* in_sizes, int n_in,
                              void* d_out, int out_size, void* d_ws, size_t ws_size,
                              hipStream_t stream) {
    const float* X  = (const float*)d_in[0];
    const float* Wq = (const float*)d_in[1];
    const float* Wk = (const float*)d_in[2];
    const float* Wv = (const float*)d_in[3];
    const float* Wo = (const float*)d_in[4];
    const float* bo = (const float*)d_in[5];
    float* out = (float*)d_out;

    const size_t HSD = (size_t)NH * S_LEN * HD;       // 4,194,304 elements
    __half* qb = (__half*)d_ws;
    __half* kb = qb + HSD;
    __half* vb = kb + HSD;
    float*  ab = (float*)(vb + HSD);                  // attn out [S][E] fp32

    gemm_qkv_kernel<<<dim3(32, 8, 3), 256, 0, stream>>>(X, Wq, Wk, Wv, qb, kb, vb);
    attn_mfma_kernel<<<dim3(64, 16), 256, 0, stream>>>(qb, kb, vb, ab);
    gemm_out_kernel<<<dim3(32, 8), 256, 0, stream>>>(ab, Wo, bo, out);
}

// Round 5
// 311.170 us; speedup vs baseline: 3.9373x; 1.9459x over previous
//
#include <hip/hip_runtime.h>
#include <hip/hip_fp16.h>

#define S_LEN 4096
#define EMB   1024
#define NH    16
#define HD    64
#define GH    8
#define WIN   256

typedef _Float16 half8 __attribute__((ext_vector_type(8)));
typedef float    f32x4 __attribute__((ext_vector_type(4)));
typedef unsigned short ushort8 __attribute__((ext_vector_type(8)));

static __device__ __forceinline__ f32x4 mfma16(half8 a, half8 b, f32x4 c) {
    return __builtin_amdgcn_mfma_f32_16x16x32_f16(a, b, c, 0, 0, 0);
}

#define GLOAD16(g, l) __builtin_amdgcn_global_load_lds( \
    (const __attribute__((address_space(1))) void*)(g), \
    (__attribute__((address_space(3))) void*)(l), 16, 0, 0)

// ---------------- split pass: fp32 -> (hi, lo) fp16 ----------------
// segments (float4 units): X[0,1M) Wq[1M,1.25M) Wk[1.25M,1.5M) Wv[1.5M,1.75M) Wo[1.75M,2M)
__global__ __launch_bounds__(256) void split_kernel(
    const float* __restrict__ X,  const float* __restrict__ Wq, const float* __restrict__ Wk,
    const float* __restrict__ Wv, const float* __restrict__ Wo,
    __half* __restrict__ Xhi, __half* __restrict__ Xlo,
    __half* __restrict__ Wh,  __half* __restrict__ Wl,
    __half* __restrict__ Woh, __half* __restrict__ Wol)
{
    const int NT = gridDim.x * blockDim.x;
    for (int i = blockIdx.x * blockDim.x + threadIdx.x; i < 2097152; i += NT) {
        const float* src; __half *dh, *dl; int off;
        if (i < 1048576)      { src = X;  dh = Xhi;           dl = Xlo;           off = i; }
        else if (i < 1310720) { src = Wq; dh = Wh;            dl = Wl;            off = i - 1048576; }
        else if (i < 1572864) { src = Wk; dh = Wh + 1048576;  dl = Wl + 1048576;  off = i - 1310720; }
        else if (i < 1835008) { src = Wv; dh = Wh + 2097152;  dl = Wl + 2097152;  off = i - 1572864; }
        else                  { src = Wo; dh = Woh;           dl = Wol;           off = i - 1835008; }
        float4 xv = *(const float4*)(src + (size_t)off * 4);
        union { __half h[4]; uint2 u; } ph, pl;
        float xs[4] = {xv.x, xv.y, xv.z, xv.w};
        #pragma unroll
        for (int j = 0; j < 4; ++j) {
            __half hj = __float2half_rn(xs[j]);
            ph.h[j] = hj;
            pl.h[j] = __float2half_rn(xs[j] - __half2float(hj));
        }
        *(uint2*)(dh + (size_t)off * 4) = ph.u;
        *(uint2*)(dl + (size_t)off * 4) = pl.u;
    }
}

// ---------------- split-fp16 MFMA GEMM: C = A * B^T (K = 1024) ----------------
// A:[M,1024] hi/lo fp16 row-major; B:[N,1024] hi/lo fp16 row-major.
// 128x128 tile, BK=64, 4 waves, per-wave 64x64 (4x4 frags of 16x16x32).
// C = Ah*Bh + Ah*Bl + Al*Bh  (lo*lo dropped: ~2^-22 rel).
// mode 0: write qkv fp16 [z*16+h][s][d] with q-scale; mode 1: write fp32 out + bias.
__global__ __launch_bounds__(256) void gemm_split_kernel(
    const __half* __restrict__ Ah_, const __half* __restrict__ Al_,
    const __half* __restrict__ Bh_, const __half* __restrict__ Bl_,
    int mode, __half* __restrict__ qkv_out,
    float* __restrict__ fo_out, const float* __restrict__ bias)
{
    __shared__ __align__(16) char lds[65536];
    char* LA_h = lds;              // [128 rows][64 k] fp16 = 16 KB, swizzled
    char* LA_l = lds + 16384;
    char* LB_h = lds + 32768;
    char* LB_l = lds + 49152;

    const int tid  = threadIdx.x;
    const int w    = tid >> 6, lane = tid & 63;
    const int bm   = blockIdx.x * 128, bn = blockIdx.y * 128;
    const int wm0  = (w & 1) * 64, wn0 = (w >> 1) * 64;
    const int lr   = lane & 15;     // frag row index
    const int lk   = lane >> 4;     // k-slot (8 halves)

    // staging geometry: chunk c = tid + i*256 -> row=c>>3, slot=c&7 (8x16B per 128B row)
    // LDS linear byte = c*16 (wave-uniform base + lane*16); global src pre-swizzled.
    const char *gAh[4], *gAl[4], *gBh[4], *gBl[4];
    int ldsoff[4];
    #pragma unroll
    for (int i = 0; i < 4; ++i) {
        const int c = tid + i * 256;
        const int row = c >> 3;
        const int sw  = ((c & 7) ^ (row & 7)) * 16;
        gAh[i] = (const char*)Ah_ + (size_t)(bm + row) * 2048 + sw;
        gAl[i] = (const char*)Al_ + (size_t)(bm + row) * 2048 + sw;
        gBh[i] = (const char*)Bh_ + (size_t)(bn + row) * 2048 + sw;
        gBl[i] = (const char*)Bl_ + (size_t)(bn + row) * 2048 + sw;
        ldsoff[i] = ((tid >> 6) * 64 + i * 256) * 16;   // wave-uniform
    }

    f32x4 acc[4][4];
    #pragma unroll
    for (int mi = 0; mi < 4; ++mi)
        #pragma unroll
        for (int ni = 0; ni < 4; ++ni) acc[mi][ni] = (f32x4){0.f, 0.f, 0.f, 0.f};

    for (int k0 = 0; k0 < 1024; k0 += 64) {
        __syncthreads();                       // prior frag reads complete
        const size_t kb = (size_t)k0 * 2;
        #pragma unroll
        for (int i = 0; i < 4; ++i) {
            GLOAD16(gAh[i] + kb, LA_h + ldsoff[i]);
            GLOAD16(gAl[i] + kb, LA_l + ldsoff[i]);
            GLOAD16(gBh[i] + kb, LB_h + ldsoff[i]);
            GLOAD16(gBl[i] + kb, LB_l + ldsoff[i]);
        }
        __syncthreads();                       // compiler drains vmcnt before barrier

        #pragma unroll
        for (int kh = 0; kh < 2; ++kh) {
            half8 afh[4], afl[4], bfh[4], bfl[4];
            #pragma unroll
            for (int f = 0; f < 4; ++f) {
                const int ar = wm0 + f * 16 + lr;
                const int ab = ar * 128 + ((kh * 64 + lk * 16) ^ ((ar & 7) << 4));
                afh[f] = *(const half8*)(LA_h + ab);
                afl[f] = *(const half8*)(LA_l + ab);
                const int br = wn0 + f * 16 + lr;
                const int bb = br * 128 + ((kh * 64 + lk * 16) ^ ((br & 7) << 4));
                bfh[f] = *(const half8*)(LB_h + bb);
                bfl[f] = *(const half8*)(LB_l + bb);
            }
            #pragma unroll
            for (int mi = 0; mi < 4; ++mi)
                #pragma unroll
                for (int ni = 0; ni < 4; ++ni) {
                    acc[mi][ni] = mfma16(afh[mi], bfh[ni], acc[mi][ni]);
                    acc[mi][ni] = mfma16(afh[mi], bfl[ni], acc[mi][ni]);
                    acc[mi][ni] = mfma16(afl[mi], bfh[ni], acc[mi][ni]);
                }
        }
    }

    // epilogue: C[m][n], m = (lane>>4)*4 + reg (1st operand rows), n = lane&15 (2nd)
    if (mode == 0) {
        #pragma unroll
        for (int ni = 0; ni < 4; ++ni) {
            const int n  = bn + wn0 + ni * 16 + lr;
            const int hg = n >> 6;              // z*16 + h
            const int d  = n & 63;
            const float alpha = ((n >> 10) == 0) ? 0.125f : 1.0f;
            __half* base = qkv_out + (size_t)hg * S_LEN * HD + d;
            #pragma unroll
            for (int mi = 0; mi < 4; ++mi) {
                const int m = bm + wm0 + mi * 16 + lk * 4;
                #pragma unroll
                for (int r = 0; r < 4; ++r)
                    base[(size_t)(m + r) * HD] = __float2half_rn(acc[mi][ni][r] * alpha);
            }
        }
    } else {
        #pragma unroll
        for (int ni = 0; ni < 4; ++ni) {
            const int n = bn + wn0 + ni * 16 + lr;
            const float bv = bias[n];
            #pragma unroll
            for (int mi = 0; mi < 4; ++mi) {
                const int m = bm + wm0 + mi * 16 + lk * 4;
                #pragma unroll
                for (int r = 0; r < 4; ++r)
                    fo_out[(size_t)(m + r) * EMB + n] = acc[mi][ni][r] + bv;
            }
        }
    }
}

// ---------------- flash attention, fp16 MFMA (swapped QK^T) ----------------
// grid (64 qblocks, 16 heads), 256 threads = 4 waves; wave w owns q rows [16w,16w+16).
// Epilogue emits O split as hi/lo fp16 for the split out-proj GEMM.
__global__ __launch_bounds__(256) void attn_mfma_kernel(
    const __half* __restrict__ q, const __half* __restrict__ k, const __half* __restrict__ v,
    __half* __restrict__ Ohi, __half* __restrict__ Olo /* [S][E] hi/lo fp16 */)
{
    __shared__ __align__(16) unsigned char smem[32768];
    char* Qs = (char*)smem;            // 8 KB
    char* Ks = (char*)smem + 8192;     // 8 KB
    char* Vt = (char*)smem + 16384;    // 8 KB
    char* Pl = (char*)smem + 24576;    // 8 KB (2 KB per wave)

    const int qb  = 63 - blockIdx.x;
    const int h   = blockIdx.y;
    const bool is_local = (h >= GH);
    const int tid  = threadIdx.x;
    const int w    = tid >> 6;
    const int lane = tid & 63;
    const int lq   = lane & 15;
    const int hi   = lane >> 4;

    const char* qh = (const char*)(q + (size_t)h * S_LEN * HD);
    const char* kh = (const char*)(k + (size_t)h * S_LEN * HD);
    const char* vh = (const char*)(v + (size_t)h * S_LEN * HD);

    #pragma unroll
    for (int e = 0; e < 2; ++e) {
        const int flat = e * 4096 + tid * 16;
        const int row  = flat >> 7;
        const int src  = flat ^ ((row & 7) << 4);
        *(uint4*)(Qs + flat) = *(const uint4*)(qh + (size_t)qb * 8192 + src);
    }
    __syncthreads();

    half8 qf[2];
    #pragma unroll
    for (int ks = 0; ks < 2; ++ks) {
        const int row = w * 16 + lq;
        int byte = row * 128 + hi * 16 + ks * 64;
        byte ^= (row & 7) << 4;
        qf[ks] = *(const half8*)(Qs + byte);
    }

    float m_run = -1e30f, l_run = 0.f;
    f32x4 po[4];
    #pragma unroll
    for (int i = 0; i < 4; ++i) po[i] = (f32x4){0.f, 0.f, 0.f, 0.f};

    const int qg = qb * 64 + w * 16 + lq;
    const int kt_lo = is_local ? ((qb - 4 > 0) ? qb - 4 : 0) : 0;
    char* plw = Pl + w * 2048;

    for (int kv = kt_lo; kv <= qb; ++kv) {
        __syncthreads();

        #pragma unroll
        for (int e = 0; e < 2; ++e) {
            const int flat = e * 4096 + tid * 16;
            const int row  = flat >> 7;
            const int src  = flat ^ ((row & 7) << 4);
            *(uint4*)(Ks + flat) = *(const uint4*)(kh + (size_t)kv * 8192 + src);
        }
        {
            const int j0 = (tid & 31) * 2;
            const int d0 = (tid >> 5) * 8;
            ushort8 v0 = *(const ushort8*)(vh + (size_t)(kv * 64 + j0)     * 128 + d0 * 2);
            ushort8 v1 = *(const ushort8*)(vh + (size_t)(kv * 64 + j0 + 1) * 128 + d0 * 2);
            #pragma unroll
            for (int i = 0; i < 8; ++i) {
                const int d = d0 + i;
                int byte = d * 128 + j0 * 2;
                byte ^= (d & 7) << 4;
                *(unsigned int*)(Vt + byte) = (unsigned int)v0[i] | ((unsigned int)v1[i] << 16);
            }
        }
        __syncthreads();

        f32x4 st[4];
        #pragma unroll
        for (int i = 0; i < 4; ++i) st[i] = (f32x4){0.f, 0.f, 0.f, 0.f};
        #pragma unroll
        for (int ks = 0; ks < 2; ++ks) {
            #pragma unroll
            for (int kt = 0; kt < 4; ++kt) {
                const int row = kt * 16 + lq;
                int byte = row * 128 + hi * 16 + ks * 64;
                byte ^= (row & 7) << 4;
                half8 kf = *(const half8*)(Ks + byte);
                st[kt] = mfma16(kf, qf[ks], st[kt]);
            }
        }

        float mx = -1e30f;
        #pragma unroll
        for (int kt = 0; kt < 4; ++kt)
            #pragma unroll
            for (int r = 0; r < 4; ++r) {
                const int kg = kv * 64 + kt * 16 + hi * 4 + r;
                const bool ok = (kg <= qg) && (!is_local || (kg + WIN >= qg));
                const float s = ok ? st[kt][r] : -1e30f;
                st[kt][r] = s;
                mx = fmaxf(mx, s);
            }
        mx = fmaxf(mx, __shfl_xor(mx, 16));
        mx = fmaxf(mx, __shfl_xor(mx, 32));
        const float mnew  = fmaxf(m_run, mx);
        const float scale = __expf(m_run - mnew);
        float lsum = 0.f;
        #pragma unroll
        for (int kt = 0; kt < 4; ++kt)
            #pragma unroll
            for (int r = 0; r < 4; ++r) {
                const float p = __expf(st[kt][r] - mnew);
                st[kt][r] = p;
                lsum += p;
            }
        lsum += __shfl_xor(lsum, 16);
        lsum += __shfl_xor(lsum, 32);
        l_run = l_run * scale + lsum;
        m_run = mnew;
        #pragma unroll
        for (int dt = 0; dt < 4; ++dt)
            #pragma unroll
            for (int r = 0; r < 4; ++r) po[dt][r] *= scale;

        #pragma unroll
        for (int kt = 0; kt < 4; ++kt) {
            int byte = lq * 128 + kt * 32 + hi * 8;
            byte ^= (lq & 7) << 4;
            union { __half2 h2[2]; uint2 u; } pu;
            pu.h2[0] = __floats2half2_rn(st[kt][0], st[kt][1]);
            pu.h2[1] = __floats2half2_rn(st[kt][2], st[kt][3]);
            *(uint2*)(plw + byte) = pu.u;
        }

        #pragma unroll
        for (int ks = 0; ks < 2; ++ks) {
            int pbyte = lq * 128 + ks * 64 + hi * 16;
            pbyte ^= (lq & 7) << 4;
            half8 pf = *(const half8*)(plw + pbyte);
            #pragma unroll
            for (int dt = 0; dt < 4; ++dt) {
                const int drow = dt * 16 + lq;
                int vbyte = drow * 128 + ks * 64 + hi * 16;
                vbyte ^= (drow & 7) << 4;
                half8 vf = *(const half8*)(Vt + vbyte);
                po[dt] = mfma16(vf, pf, po[dt]);
            }
        }
    }

    const float linv = 1.0f / l_run;
    __half* oh = Ohi + (size_t)qg * EMB + h * HD;
    __half* ol = Olo + (size_t)qg * EMB + h * HD;
    #pragma unroll
    for (int dt = 0; dt < 4; ++dt)
        #pragma unroll
        for (int r = 0; r < 4; ++r) {
            const float vfull = po[dt][r] * linv;
            const __half vhi = __float2half_rn(vfull);
            oh[dt * 16 + hi * 4 + r] = vhi;
            ol[dt * 16 + hi * 4 + r] = __float2half_rn(vfull - __half2float(vhi));
        }
}

extern "C" void kernel_launch(void* const* d_in, const int* in_sizes, int n_in,
                              void* d_out, int out_size, void* d_ws, size_t ws_size,
                              hipStream_t stream) {
    const float* X  = (const float*)d_in[0];
    const float* Wq = (const float*)d_in[1];
    const float* Wk = (const float*)d_in[2];
    const float* Wv = (const float*)d_in[3];
    const float* Wo = (const float*)d_in[4];
    const float* bo = (const float*)d_in[5];
    float* out = (float*)d_out;

    // workspace layout (halves): 56 MB total
    __half* ws   = (__half*)d_ws;
    __half* qkvb = ws;                          // [3][16][4096][64] = 12M halves
    __half* XOhi = ws + 12582912;               // X-hi, later O-hi  (4M)
    __half* XOlo = ws + 16777216;               // X-lo, later O-lo  (4M)
    __half* Wh   = ws + 20971520;               // Wq|Wk|Wv hi (3M)
    __half* Wl   = ws + 24117248;               // (3M)
    __half* Woh  = ws + 27262976;               // (1M)
    __half* Wol  = ws + 28311552;               // (1M) -> end 29360128 halves

    split_kernel<<<dim3(2048), 256, 0, stream>>>(X, Wq, Wk, Wv, Wo,
                                                 XOhi, XOlo, Wh, Wl, Woh, Wol);
    // QKV: M=4096, N=3072 (Wq|Wk|Wv), K=1024
    gemm_split_kernel<<<dim3(32, 24), 256, 0, stream>>>(XOhi, XOlo, Wh, Wl,
                                                        0, qkvb, nullptr, nullptr);
    attn_mfma_kernel<<<dim3(64, 16), 256, 0, stream>>>(qkvb, qkvb + 4194304, qkvb + 8388608,
                                                       XOhi, XOlo);
    // out-proj: M=4096, N=1024, K=1024
    gemm_split_kernel<<<dim3(32, 8), 256, 0, stream>>>(XOhi, XOlo, Woh, Wol,
                                                       1, nullptr, out, bo);
}

// Round 8
// 262.883 us; speedup vs baseline: 4.6605x; 1.1837x over previous
//
#include <hip/hip_runtime.h>
#include <hip/hip_fp16.h>

#define S_LEN 4096
#define EMB   1024
#define NH    16
#define HD    64
#define GH    8
#define WIN   256

typedef _Float16 half8 __attribute__((ext_vector_type(8)));
typedef float    f32x4 __attribute__((ext_vector_type(4)));
typedef unsigned short ushort8 __attribute__((ext_vector_type(8)));

static __device__ __forceinline__ f32x4 mfma16(half8 a, half8 b, f32x4 c) {
    return __builtin_amdgcn_mfma_f32_16x16x32_f16(a, b, c, 0, 0, 0);
}

#define GLOAD16(g, l) __builtin_amdgcn_global_load_lds( \
    (const __attribute__((address_space(1))) void*)(g), \
    (__attribute__((address_space(3))) void*)(l), 16, 0, 0)

// ---------------- split pass: fp32 -> (hi, lo) fp16 ----------------
__global__ __launch_bounds__(256) void split_kernel(
    const float* __restrict__ X,  const float* __restrict__ Wq, const float* __restrict__ Wk,
    const float* __restrict__ Wv, const float* __restrict__ Wo,
    __half* __restrict__ Xhi, __half* __restrict__ Xlo,
    __half* __restrict__ Wh,  __half* __restrict__ Wl,
    __half* __restrict__ Woh, __half* __restrict__ Wol)
{
    const int NT = gridDim.x * blockDim.x;
    for (int i = blockIdx.x * blockDim.x + threadIdx.x; i < 2097152; i += NT) {
        const float* src; __half *dh, *dl; int off;
        if (i < 1048576)      { src = X;  dh = Xhi;           dl = Xlo;           off = i; }
        else if (i < 1310720) { src = Wq; dh = Wh;            dl = Wl;            off = i - 1048576; }
        else if (i < 1572864) { src = Wk; dh = Wh + 1048576;  dl = Wl + 1048576;  off = i - 1310720; }
        else if (i < 1835008) { src = Wv; dh = Wh + 2097152;  dl = Wl + 2097152;  off = i - 1572864; }
        else                  { src = Wo; dh = Woh;           dl = Wol;           off = i - 1835008; }
        float4 xv = *(const float4*)(src + (size_t)off * 4);
        union { __half h[4]; uint2 u; } ph, pl;
        float xs[4] = {xv.x, xv.y, xv.z, xv.w};
        #pragma unroll
        for (int j = 0; j < 4; ++j) {
            __half hj = __float2half_rn(xs[j]);
            ph.h[j] = hj;
            pl.h[j] = __float2half_rn(xs[j] - __half2float(hj));
        }
        *(uint2*)(dh + (size_t)off * 4) = ph.u;
        *(uint2*)(dl + (size_t)off * 4) = pl.u;
    }
}

// ---------------- split-fp16 MFMA GEMM: C = A * B^T (K = 1024) ----------------
__global__ __launch_bounds__(256) void gemm_split_kernel(
    const __half* __restrict__ Ah_, const __half* __restrict__ Al_,
    const __half* __restrict__ Bh_, const __half* __restrict__ Bl_,
    int mode, __half* __restrict__ qkv_out,
    float* __restrict__ fo_out, const float* __restrict__ bias)
{
    __shared__ __align__(16) char lds[65536];
    char* LA_h = lds;
    char* LA_l = lds + 16384;
    char* LB_h = lds + 32768;
    char* LB_l = lds + 49152;

    const int tid  = threadIdx.x;
    const int w    = tid >> 6, lane = tid & 63;
    const int bm   = blockIdx.x * 128, bn = blockIdx.y * 128;
    const int wm0  = (w & 1) * 64, wn0 = (w >> 1) * 64;
    const int lr   = lane & 15;
    const int lk   = lane >> 4;

    const char *gAh[4], *gAl[4], *gBh[4], *gBl[4];
    int ldsoff[4];
    #pragma unroll
    for (int i = 0; i < 4; ++i) {
        const int c = tid + i * 256;
        const int row = c >> 3;
        const int sw  = ((c & 7) ^ (row & 7)) * 16;
        gAh[i] = (const char*)Ah_ + (size_t)(bm + row) * 2048 + sw;
        gAl[i] = (const char*)Al_ + (size_t)(bm + row) * 2048 + sw;
        gBh[i] = (const char*)Bh_ + (size_t)(bn + row) * 2048 + sw;
        gBl[i] = (const char*)Bl_ + (size_t)(bn + row) * 2048 + sw;
        ldsoff[i] = ((tid >> 6) * 64 + i * 256) * 16;
    }

    f32x4 acc[4][4];
    #pragma unroll
    for (int mi = 0; mi < 4; ++mi)
        #pragma unroll
        for (int ni = 0; ni < 4; ++ni) acc[mi][ni] = (f32x4){0.f, 0.f, 0.f, 0.f};

    for (int k0 = 0; k0 < 1024; k0 += 64) {
        __syncthreads();
        const size_t kb = (size_t)k0 * 2;
        #pragma unroll
        for (int i = 0; i < 4; ++i) {
            GLOAD16(gAh[i] + kb, LA_h + ldsoff[i]);
            GLOAD16(gAl[i] + kb, LA_l + ldsoff[i]);
            GLOAD16(gBh[i] + kb, LB_h + ldsoff[i]);
            GLOAD16(gBl[i] + kb, LB_l + ldsoff[i]);
        }
        __syncthreads();

        #pragma unroll
        for (int kh = 0; kh < 2; ++kh) {
            half8 afh[4], afl[4], bfh[4], bfl[4];
            #pragma unroll
            for (int f = 0; f < 4; ++f) {
                const int ar = wm0 + f * 16 + lr;
                const int ab = ar * 128 + ((kh * 64 + lk * 16) ^ ((ar & 7) << 4));
                afh[f] = *(const half8*)(LA_h + ab);
                afl[f] = *(const half8*)(LA_l + ab);
                const int br = wn0 + f * 16 + lr;
                const int bb = br * 128 + ((kh * 64 + lk * 16) ^ ((br & 7) << 4));
                bfh[f] = *(const half8*)(LB_h + bb);
                bfl[f] = *(const half8*)(LB_l + bb);
            }
            #pragma unroll
            for (int mi = 0; mi < 4; ++mi)
                #pragma unroll
                for (int ni = 0; ni < 4; ++ni) {
                    acc[mi][ni] = mfma16(afh[mi], bfh[ni], acc[mi][ni]);
                    acc[mi][ni] = mfma16(afh[mi], bfl[ni], acc[mi][ni]);
                    acc[mi][ni] = mfma16(afl[mi], bfh[ni], acc[mi][ni]);
                }
        }
    }

    if (mode == 0) {
        #pragma unroll
        for (int ni = 0; ni < 4; ++ni) {
            const int n  = bn + wn0 + ni * 16 + lr;
            const int hg = n >> 6;
            const int d  = n & 63;
            const float alpha = ((n >> 10) == 0) ? 0.125f : 1.0f;
            __half* base = qkv_out + (size_t)hg * S_LEN * HD + d;
            #pragma unroll
            for (int mi = 0; mi < 4; ++mi) {
                const int m = bm + wm0 + mi * 16 + lk * 4;
                #pragma unroll
                for (int r = 0; r < 4; ++r)
                    base[(size_t)(m + r) * HD] = __float2half_rn(acc[mi][ni][r] * alpha);
            }
        }
    } else {
        #pragma unroll
        for (int ni = 0; ni < 4; ++ni) {
            const int n = bn + wn0 + ni * 16 + lr;
            const float bv = bias[n];
            #pragma unroll
            for (int mi = 0; mi < 4; ++mi) {
                const int m = bm + wm0 + mi * 16 + lk * 4;
                #pragma unroll
                for (int r = 0; r < 4; ++r)
                    fo_out[(size_t)(m + r) * EMB + n] = acc[mi][ni][r] + bv;
            }
        }
    }
}

// ---------------- attention pass 1: split-KV flash, fp16 MFMA ----------------
// grid (224, 8), 256 thr = 4 waves.
//  x in [0,160): global head h=y, work item i=159-x -> (qb, chunk of 16 KV tiles).
//                nc(qb)=qb/16+1. qb<16 (nc==1): direct O write. Else partial.
//  x in [160,224): local head h=8+y, qb=x-160, window tiles, direct O write.
__global__ __launch_bounds__(256) void attn_pass1(
    const __half* __restrict__ q, const __half* __restrict__ k, const __half* __restrict__ v,
    __half* __restrict__ Ohi, __half* __restrict__ Olo,
    float* __restrict__ partO, float* __restrict__ partML)
{
    __shared__ __align__(16) unsigned char smem[32768];
    char* Qs = (char*)smem;
    char* Ks = (char*)smem + 8192;
    char* Vt = (char*)smem + 16384;
    char* Pl = (char*)smem + 24576;

    int h, qb, kt_lo, kt_hi, pslot = 0;
    bool is_local, direct;
    if (blockIdx.x < 160) {
        h = blockIdx.y;
        is_local = false;
        const int i = 159 - blockIdx.x;          // heaviest chunks dispatch first
        int c;
        if (i < 16)      { qb = i;                c = 0; }
        else if (i < 48) { const int t = i - 16;  qb = 16 + (t >> 1); c = t & 1; }
        else if (i < 96) { const int t = i - 48;  qb = 32 + t / 3;    c = t % 3; }
        else             { const int t = i - 96;  qb = 48 + (t >> 2); c = t & 3; }
        kt_lo = c * 16;
        kt_hi = (kt_lo + 15 < qb) ? kt_lo + 15 : qb;
        direct = (qb < 16);
        pslot  = (h * 48 + (qb - 16)) * 4 + c;   // only used when !direct
    } else {
        h  = 8 + blockIdx.y;
        qb = blockIdx.x - 160;
        is_local = true;
        kt_lo = (qb - 4 > 0) ? qb - 4 : 0;
        kt_hi = qb;
        direct = true;
    }

    const int tid  = threadIdx.x;
    const int w    = tid >> 6;
    const int lane = tid & 63;
    const int lq   = lane & 15;
    const int hi   = lane >> 4;

    const char* qh = (const char*)(q + (size_t)h * S_LEN * HD);
    const char* kh = (const char*)(k + (size_t)h * S_LEN * HD);
    const char* vh = (const char*)(v + (size_t)h * S_LEN * HD);

    #pragma unroll
    for (int e = 0; e < 2; ++e) {
        const int flat = e * 4096 + tid * 16;
        const int row  = flat >> 7;
        const int src  = flat ^ ((row & 7) << 4);
        *(uint4*)(Qs + flat) = *(const uint4*)(qh + (size_t)qb * 8192 + src);
    }
    __syncthreads();

    half8 qf[2];
    #pragma unroll
    for (int ks = 0; ks < 2; ++ks) {
        const int row = w * 16 + lq;
        int byte = row * 128 + hi * 16 + ks * 64;
        byte ^= (row & 7) << 4;
        qf[ks] = *(const half8*)(Qs + byte);
    }

    float m_run = -1e30f, l_run = 0.f;
    f32x4 po[4];
    #pragma unroll
    for (int i = 0; i < 4; ++i) po[i] = (f32x4){0.f, 0.f, 0.f, 0.f};

    const int qg = qb * 64 + w * 16 + lq;
    char* plw = Pl + w * 2048;

    for (int kv = kt_lo; kv <= kt_hi; ++kv) {
        __syncthreads();

        #pragma unroll
        for (int e = 0; e < 2; ++e) {
            const int flat = e * 4096 + tid * 16;
            const int row  = flat >> 7;
            const int src  = flat ^ ((row & 7) << 4);
            *(uint4*)(Ks + flat) = *(const uint4*)(kh + (size_t)kv * 8192 + src);
        }
        {
            const int j0 = (tid & 31) * 2;
            const int d0 = (tid >> 5) * 8;
            ushort8 v0 = *(const ushort8*)(vh + (size_t)(kv * 64 + j0)     * 128 + d0 * 2);
            ushort8 v1 = *(const ushort8*)(vh + (size_t)(kv * 64 + j0 + 1) * 128 + d0 * 2);
            #pragma unroll
            for (int i = 0; i < 8; ++i) {
                const int d = d0 + i;
                int byte = d * 128 + j0 * 2;
                byte ^= (d & 7) << 4;
                *(unsigned int*)(Vt + byte) = (unsigned int)v0[i] | ((unsigned int)v1[i] << 16);
            }
        }
        __syncthreads();

        f32x4 st[4];
        #pragma unroll
        for (int i = 0; i < 4; ++i) st[i] = (f32x4){0.f, 0.f, 0.f, 0.f};
        #pragma unroll
        for (int ks = 0; ks < 2; ++ks) {
            #pragma unroll
            for (int kt = 0; kt < 4; ++kt) {
                const int row = kt * 16 + lq;
                int byte = row * 128 + hi * 16 + ks * 64;
                byte ^= (row & 7) << 4;
                half8 kf = *(const half8*)(Ks + byte);
                st[kt] = mfma16(kf, qf[ks], st[kt]);
            }
        }

        float mx = -1e30f;
        #pragma unroll
        for (int kt = 0; kt < 4; ++kt)
            #pragma unroll
            for (int r = 0; r < 4; ++r) {
                const int kg = kv * 64 + kt * 16 + hi * 4 + r;
                const bool ok = (kg <= qg) && (!is_local || (kg + WIN >= qg));
                const float s = ok ? st[kt][r] : -1e30f;
                st[kt][r] = s;
                mx = fmaxf(mx, s);
            }
        mx = fmaxf(mx, __shfl_xor(mx, 16));
        mx = fmaxf(mx, __shfl_xor(mx, 32));
        const float mnew  = fmaxf(m_run, mx);
        const float scale = __expf(m_run - mnew);
        float lsum = 0.f;
        #pragma unroll
        for (int kt = 0; kt < 4; ++kt)
            #pragma unroll
            for (int r = 0; r < 4; ++r) {
                const float p = __expf(st[kt][r] - mnew);
                st[kt][r] = p;
                lsum += p;
            }
        lsum += __shfl_xor(lsum, 16);
        lsum += __shfl_xor(lsum, 32);
        l_run = l_run * scale + lsum;
        m_run = mnew;
        #pragma unroll
        for (int dt = 0; dt < 4; ++dt)
            #pragma unroll
            for (int r = 0; r < 4; ++r) po[dt][r] *= scale;

        #pragma unroll
        for (int kt = 0; kt < 4; ++kt) {
            int byte = lq * 128 + kt * 32 + hi * 8;
            byte ^= (lq & 7) << 4;
            union { __half2 h2[2]; uint2 u; } pu;
            pu.h2[0] = __floats2half2_rn(st[kt][0], st[kt][1]);
            pu.h2[1] = __floats2half2_rn(st[kt][2], st[kt][3]);
            *(uint2*)(plw + byte) = pu.u;
        }

        #pragma unroll
        for (int ks = 0; ks < 2; ++ks) {
            int pbyte = lq * 128 + ks * 64 + hi * 16;
            pbyte ^= (lq & 7) << 4;
            half8 pf = *(const half8*)(plw + pbyte);
            #pragma unroll
            for (int dt = 0; dt < 4; ++dt) {
                const int drow = dt * 16 + lq;
                int vbyte = drow * 128 + ks * 64 + hi * 16;
                vbyte ^= (drow & 7) << 4;
                half8 vf = *(const half8*)(Vt + vbyte);
                po[dt] = mfma16(vf, pf, po[dt]);
            }
        }
    }

    if (direct) {
        const float linv = 1.0f / l_run;
        __half* oh = Ohi + (size_t)qg * EMB + h * HD;
        __half* ol = Olo + (size_t)qg * EMB + h * HD;
        #pragma unroll
        for (int dt = 0; dt < 4; ++dt)
            #pragma unroll
            for (int r = 0; r < 4; ++r) {
                const float vfull = po[dt][r] * linv;
                const __half vhi = __float2half_rn(vfull);
                oh[dt * 16 + hi * 4 + r] = vhi;
                ol[dt * 16 + hi * 4 + r] = __float2half_rn(vfull - __half2float(vhi));
            }
    } else {
        float* op = partO + (size_t)pslot * 4096 + (w * 16 + lq) * 64;
        #pragma unroll
        for (int dt = 0; dt < 4; ++dt)
            #pragma unroll
            for (int r = 0; r < 4; ++r)
                op[dt * 16 + hi * 4 + r] = po[dt][r];
        if (hi == 0) {
            partML[(size_t)pslot * 128 + (w * 16 + lq) * 2]     = m_run;
            partML[(size_t)pslot * 128 + (w * 16 + lq) * 2 + 1] = l_run;
        }
    }
}

// ---------------- attention pass 2: combine partials (global heads, qb>=16) ----
// grid (48, 8): qb = 16+bx, h = by. 256 thr: row = tid>>2 (64), d0 = (tid&3)*16.
__global__ __launch_bounds__(256) void attn_combine(
    const float* __restrict__ partO, const float* __restrict__ partML,
    __half* __restrict__ Ohi, __half* __restrict__ Olo)
{
    const int qb = 16 + blockIdx.x;
    const int h  = blockIdx.y;
    const int nc = (qb >> 4) + 1;
    const int row = threadIdx.x >> 2;
    const int d0  = (threadIdx.x & 3) * 16;
    const int base_slot = (h * 48 + (qb - 16)) * 4;

    float M = -1e30f, mv[4], lv[4];
    #pragma unroll
    for (int i = 0; i < 4; ++i)
        if (i < nc) {
            mv[i] = partML[(size_t)(base_slot + i) * 128 + row * 2];
            lv[i] = partML[(size_t)(base_slot + i) * 128 + row * 2 + 1];
            M = fmaxf(M, mv[i]);
        }
    float L = 0.f, wgt[4];
    #pragma unroll
    for (int i = 0; i < 4; ++i)
        if (i < nc) {
            wgt[i] = __expf(mv[i] - M);
            L += lv[i] * wgt[i];
        }

    float o[16];
    #pragma unroll
    for (int j = 0; j < 16; ++j) o[j] = 0.f;
    #pragma unroll
    for (int i = 0; i < 4; ++i)
        if (i < nc) {
            const float* src = partO + (size_t)(base_slot + i) * 4096 + row * 64 + d0;
            const float wi = wgt[i];
            #pragma unroll
            for (int j4 = 0; j4 < 4; ++j4) {
                float4 s4 = *(const float4*)(src + j4 * 4);
                o[j4*4+0] = fmaf(wi, s4.x, o[j4*4+0]);
                o[j4*4+1] = fmaf(wi, s4.y, o[j4*4+1]);
                o[j4*4+2] = fmaf(wi, s4.z, o[j4*4+2]);
                o[j4*4+3] = fmaf(wi, s4.w, o[j4*4+3]);
            }
        }
    const float Linv = 1.0f / L;
    ushort8 ph[2], pl[2];
    #pragma unroll
    for (int j = 0; j < 16; ++j) {
        const float vfull = o[j] * Linv;
        const __half vhi = __float2half_rn(vfull);
        ph[j >> 3][j & 7] = __half_as_ushort(vhi);
        pl[j >> 3][j & 7] = __half_as_ushort(__float2half_rn(vfull - __half2float(vhi)));
    }
    const size_t ob = (size_t)(qb * 64 + row) * EMB + h * HD + d0;
    *(ushort8*)((__half*)Ohi + ob)     = ph[0];
    *(ushort8*)((__half*)Ohi + ob + 8) = ph[1];
    *(ushort8*)((__half*)Olo + ob)     = pl[0];
    *(ushort8*)((__half*)Olo + ob + 8) = pl[1];
}

extern "C" void kernel_launch(void* const* d_in, const int* in_sizes, int n_in,
                              void* d_out, int out_size, void* d_ws, size_t ws_size,
                              hipStream_t stream) {
    const float* X  = (const float*)d_in[0];
    const float* Wq = (const float*)d_in[1];
    const float* Wk = (const float*)d_in[2];
    const float* Wv = (const float*)d_in[3];
    const float* Wo = (const float*)d_in[4];
    const float* bo = (const float*)d_in[5];
    float* out = (float*)d_out;

    // workspace (halves). partO/partML alias Wh/Wl, which die after the QKV GEMM.
    __half* ws   = (__half*)d_ws;
    __half* qkvb = ws;                          // [3*16][4096][64]  12,582,912 h
    __half* XOhi = ws + 12582912;               // X-hi then O-hi     4,194,304 h
    __half* XOlo = ws + 16777216;               // X-lo then O-lo     4,194,304 h
    __half* Woh  = ws + 20971520;               //                    1,048,576 h
    __half* Wol  = ws + 22020096;               //                    1,048,576 h
    __half* Wh   = ws + 23068672;               // Wq|Wk|Wv hi        3,145,728 h
    __half* Wl   = ws + 26214400;               //                    3,145,728 h
    float* partO  = (float*)(ws + 23068672);    // 8*48*4 slots * 4096 = 6,291,456 f
    float* partML = partO + 6291456;            // 8*48*4 * 128        =   196,608 f
    // total ws footprint ~ 69 MB

    split_kernel<<<dim3(2048), 256, 0, stream>>>(X, Wq, Wk, Wv, Wo,
                                                 XOhi, XOlo, Wh, Wl, Woh, Wol);
    gemm_split_kernel<<<dim3(32, 24), 256, 0, stream>>>(XOhi, XOlo, Wh, Wl,
                                                        0, qkvb, nullptr, nullptr);
    attn_pass1<<<dim3(224, 8), 256, 0, stream>>>(qkvb, qkvb + 4194304, qkvb + 8388608,
                                                 XOhi, XOlo, partO, partML);
    attn_combine<<<dim3(48, 8), 256, 0, stream>>>(partO, partML, XOhi, XOlo);
    gemm_split_kernel<<<dim3(32, 8), 256, 0, stream>>>(XOhi, XOlo, Woh, Wol,
                                                       1, nullptr, out, bo);
}

// Round 11
// 255.188 us; speedup vs baseline: 4.8010x; 1.0302x over previous
//
#include <hip/hip_runtime.h>
#include <hip/hip_fp16.h>

#define S_LEN 4096
#define EMB   1024
#define NH    16
#define HD    64
#define GH    8
#define WIN   256

typedef _Float16 half8 __attribute__((ext_vector_type(8)));
typedef float    f32x4 __attribute__((ext_vector_type(4)));
typedef unsigned short ushort8 __attribute__((ext_vector_type(8)));

static __device__ __forceinline__ f32x4 mfma16(half8 a, half8 b, f32x4 c) {
    return __builtin_amdgcn_mfma_f32_16x16x32_f16(a, b, c, 0, 0, 0);
}

#define GLOAD16(g, l) __builtin_amdgcn_global_load_lds( \
    (const __attribute__((address_space(1))) void*)(g), \
    (__attribute__((address_space(3))) void*)(l), 16, 0, 0)

// ---------------- split pass: fp32 -> (hi, lo) fp16 ----------------
__global__ __launch_bounds__(256) void split_kernel(
    const float* __restrict__ X,  const float* __restrict__ Wq, const float* __restrict__ Wk,
    const float* __restrict__ Wv, const float* __restrict__ Wo,
    __half* __restrict__ Xhi, __half* __restrict__ Xlo,
    __half* __restrict__ Wh,  __half* __restrict__ Wl,
    __half* __restrict__ Woh, __half* __restrict__ Wol)
{
    const int NT = gridDim.x * blockDim.x;
    for (int i = blockIdx.x * blockDim.x + threadIdx.x; i < 2097152; i += NT) {
        const float* src; __half *dh, *dl; int off;
        if (i < 1048576)      { src = X;  dh = Xhi;           dl = Xlo;           off = i; }
        else if (i < 1310720) { src = Wq; dh = Wh;            dl = Wl;            off = i - 1048576; }
        else if (i < 1572864) { src = Wk; dh = Wh + 1048576;  dl = Wl + 1048576;  off = i - 1310720; }
        else if (i < 1835008) { src = Wv; dh = Wh + 2097152;  dl = Wl + 2097152;  off = i - 1572864; }
        else                  { src = Wo; dh = Woh;           dl = Wol;           off = i - 1835008; }
        float4 xv = *(const float4*)(src + (size_t)off * 4);
        union { __half h[4]; uint2 u; } ph, pl;
        float xs[4] = {xv.x, xv.y, xv.z, xv.w};
        #pragma unroll
        for (int j = 0; j < 4; ++j) {
            __half hj = __float2half_rn(xs[j]);
            ph.h[j] = hj;
            pl.h[j] = __float2half_rn(xs[j] - __half2float(hj));
        }
        *(uint2*)(dh + (size_t)off * 4) = ph.u;
        *(uint2*)(dl + (size_t)off * 4) = pl.u;
    }
}

// ---------------- split-fp16 MFMA GEMM (QKV): C = A * B^T (K = 1024) ----------------
__global__ __launch_bounds__(256) void gemm_split_kernel(
    const __half* __restrict__ Ah_, const __half* __restrict__ Al_,
    const __half* __restrict__ Bh_, const __half* __restrict__ Bl_,
    int mode, __half* __restrict__ qkv_out,
    float* __restrict__ fo_out, const float* __restrict__ bias)
{
    __shared__ __align__(16) char lds[65536];
    char* LA_h = lds;
    char* LA_l = lds + 16384;
    char* LB_h = lds + 32768;
    char* LB_l = lds + 49152;

    const int tid  = threadIdx.x;
    const int w    = tid >> 6, lane = tid & 63;
    const int bm   = blockIdx.x * 128, bn = blockIdx.y * 128;
    const int wm0  = (w & 1) * 64, wn0 = (w >> 1) * 64;
    const int lr   = lane & 15;
    const int lk   = lane >> 4;

    const char *gAh[4], *gAl[4], *gBh[4], *gBl[4];
    int ldsoff[4];
    #pragma unroll
    for (int i = 0; i < 4; ++i) {
        const int c = tid + i * 256;
        const int row = c >> 3;
        const int sw  = ((c & 7) ^ (row & 7)) * 16;
        gAh[i] = (const char*)Ah_ + (size_t)(bm + row) * 2048 + sw;
        gAl[i] = (const char*)Al_ + (size_t)(bm + row) * 2048 + sw;
        gBh[i] = (const char*)Bh_ + (size_t)(bn + row) * 2048 + sw;
        gBl[i] = (const char*)Bl_ + (size_t)(bn + row) * 2048 + sw;
        ldsoff[i] = ((tid >> 6) * 64 + i * 256) * 16;
    }

    f32x4 acc[4][4];
    #pragma unroll
    for (int mi = 0; mi < 4; ++mi)
        #pragma unroll
        for (int ni = 0; ni < 4; ++ni) acc[mi][ni] = (f32x4){0.f, 0.f, 0.f, 0.f};

    for (int k0 = 0; k0 < 1024; k0 += 64) {
        __syncthreads();
        const size_t kb = (size_t)k0 * 2;
        #pragma unroll
        for (int i = 0; i < 4; ++i) {
            GLOAD16(gAh[i] + kb, LA_h + ldsoff[i]);
            GLOAD16(gAl[i] + kb, LA_l + ldsoff[i]);
            GLOAD16(gBh[i] + kb, LB_h + ldsoff[i]);
            GLOAD16(gBl[i] + kb, LB_l + ldsoff[i]);
        }
        __syncthreads();

        #pragma unroll
        for (int kh = 0; kh < 2; ++kh) {
            half8 afh[4], afl[4], bfh[4], bfl[4];
            #pragma unroll
            for (int f = 0; f < 4; ++f) {
                const int ar = wm0 + f * 16 + lr;
                const int ab = ar * 128 + ((kh * 64 + lk * 16) ^ ((ar & 7) << 4));
                afh[f] = *(const half8*)(LA_h + ab);
                afl[f] = *(const half8*)(LA_l + ab);
                const int br = wn0 + f * 16 + lr;
                const int bb = br * 128 + ((kh * 64 + lk * 16) ^ ((br & 7) << 4));
                bfh[f] = *(const half8*)(LB_h + bb);
                bfl[f] = *(const half8*)(LB_l + bb);
            }
            #pragma unroll
            for (int mi = 0; mi < 4; ++mi)
                #pragma unroll
                for (int ni = 0; ni < 4; ++ni) {
                    acc[mi][ni] = mfma16(afh[mi], bfh[ni], acc[mi][ni]);
                    acc[mi][ni] = mfma16(afh[mi], bfl[ni], acc[mi][ni]);
                    acc[mi][ni] = mfma16(afl[mi], bfh[ni], acc[mi][ni]);
                }
        }
    }

    if (mode == 0) {
        #pragma unroll
        for (int ni = 0; ni < 4; ++ni) {
            const int n  = bn + wn0 + ni * 16 + lr;
            const int hg = n >> 6;
            const int d  = n & 63;
            const float alpha = ((n >> 10) == 0) ? 0.125f : 1.0f;
            __half* base = qkv_out + (size_t)hg * S_LEN * HD + d;
            #pragma unroll
            for (int mi = 0; mi < 4; ++mi) {
                const int m = bm + wm0 + mi * 16 + lk * 4;
                #pragma unroll
                for (int r = 0; r < 4; ++r)
                    base[(size_t)(m + r) * HD] = __float2half_rn(acc[mi][ni][r] * alpha);
            }
        }
    } else {
        #pragma unroll
        for (int ni = 0; ni < 4; ++ni) {
            const int n = bn + wn0 + ni * 16 + lr;
            const float bv = bias[n];
            #pragma unroll
            for (int mi = 0; mi < 4; ++mi) {
                const int m = bm + wm0 + mi * 16 + lk * 4;
                #pragma unroll
                for (int r = 0; r < 4; ++r)
                    fo_out[(size_t)(m + r) * EMB + n] = acc[mi][ni][r] + bv;
            }
        }
    }
}

// ------- out-proj GEMM: 128x64 tile (512 blocks -> 2/CU for stall overlap) -------
// Same BK=64 / swizzle / 3-MFMA split inner loop and identical K-accumulation
// order as gemm_split_kernel mode 1 -> bitwise-identical output.
__global__ __launch_bounds__(256) void gemm_split_out_kernel(
    const __half* __restrict__ Ah_, const __half* __restrict__ Al_,
    const __half* __restrict__ Bh_, const __half* __restrict__ Bl_,
    float* __restrict__ fo_out, const float* __restrict__ bias)
{
    __shared__ __align__(16) char lds[49152];
    char* LA_h = lds;              // [128][64] fp16 = 16 KB
    char* LA_l = lds + 16384;      // 16 KB
    char* LB_h = lds + 32768;      // [64][64] fp16 = 8 KB
    char* LB_l = lds + 40960;      // 8 KB

    const int tid  = threadIdx.x;
    const int w    = tid >> 6, lane = tid & 63;
    const int bm   = blockIdx.x * 128, bn = blockIdx.y * 64;
    const int wm0  = (w & 1) * 64, wn0 = (w >> 1) * 32;
    const int lr   = lane & 15;
    const int lk   = lane >> 4;

    const char *gAh[4], *gAl[4], *gBh[2], *gBl[2];
    int ldsoffA[4], ldsoffB[2];
    #pragma unroll
    for (int i = 0; i < 4; ++i) {
        const int c = tid + i * 256;
        const int row = c >> 3;
        const int sw  = ((c & 7) ^ (row & 7)) * 16;
        gAh[i] = (const char*)Ah_ + (size_t)(bm + row) * 2048 + sw;
        gAl[i] = (const char*)Al_ + (size_t)(bm + row) * 2048 + sw;
        ldsoffA[i] = (w * 64 + i * 256) * 16;
    }
    #pragma unroll
    for (int i = 0; i < 2; ++i) {
        const int c = tid + i * 256;
        const int row = c >> 3;                 // 0..63
        const int sw  = ((c & 7) ^ (row & 7)) * 16;
        gBh[i] = (const char*)Bh_ + (size_t)(bn + row) * 2048 + sw;
        gBl[i] = (const char*)Bl_ + (size_t)(bn + row) * 2048 + sw;
        ldsoffB[i] = (w * 64 + i * 256) * 16;
    }

    f32x4 acc[4][2];
    #pragma unroll
    for (int mi = 0; mi < 4; ++mi)
        #pragma unroll
        for (int ni = 0; ni < 2; ++ni) acc[mi][ni] = (f32x4){0.f, 0.f, 0.f, 0.f};

    for (int k0 = 0; k0 < 1024; k0 += 64) {
        __syncthreads();
        const size_t kb = (size_t)k0 * 2;
        #pragma unroll
        for (int i = 0; i < 4; ++i) {
            GLOAD16(gAh[i] + kb, LA_h + ldsoffA[i]);
            GLOAD16(gAl[i] + kb, LA_l + ldsoffA[i]);
        }
        #pragma unroll
        for (int i = 0; i < 2; ++i) {
            GLOAD16(gBh[i] + kb, LB_h + ldsoffB[i]);
            GLOAD16(gBl[i] + kb, LB_l + ldsoffB[i]);
        }
        __syncthreads();

        #pragma unroll
        for (int kh = 0; kh < 2; ++kh) {
            half8 afh[4], afl[4], bfh[2], bfl[2];
            #pragma unroll
            for (int f = 0; f < 4; ++f) {
                const int ar = wm0 + f * 16 + lr;
                const int ab = ar * 128 + ((kh * 64 + lk * 16) ^ ((ar & 7) << 4));
                afh[f] = *(const half8*)(LA_h + ab);
                afl[f] = *(const half8*)(LA_l + ab);
            }
            #pragma unroll
            for (int ni = 0; ni < 2; ++ni) {
                const int br = wn0 + ni * 16 + lr;
                const int bb = br * 128 + ((kh * 64 + lk * 16) ^ ((br & 7) << 4));
                bfh[ni] = *(const half8*)(LB_h + bb);
                bfl[ni] = *(const half8*)(LB_l + bb);
            }
            #pragma unroll
            for (int mi = 0; mi < 4; ++mi)
                #pragma unroll
                for (int ni = 0; ni < 2; ++ni) {
                    acc[mi][ni] = mfma16(afh[mi], bfh[ni], acc[mi][ni]);
                    acc[mi][ni] = mfma16(afh[mi], bfl[ni], acc[mi][ni]);
                    acc[mi][ni] = mfma16(afl[mi], bfh[ni], acc[mi][ni]);
                }
        }
    }

    #pragma unroll
    for (int ni = 0; ni < 2; ++ni) {
        const int n = bn + wn0 + ni * 16 + lr;
        const float bv = bias[n];
        #pragma unroll
        for (int mi = 0; mi < 4; ++mi) {
            const int m = bm + wm0 + mi * 16 + lk * 4;
            #pragma unroll
            for (int r = 0; r < 4; ++r)
                fo_out[(size_t)(m + r) * EMB + n] = acc[mi][ni][r] + bv;
        }
    }
}

// ---------------- attention pass 1: split-KV flash, fp16 MFMA ----------------
// grid (224, 8), 256 thr = 4 waves.
//  x in [0,160): global head h=y, work item i=159-x -> (qb, chunk of 16 KV tiles).
//                nc(qb)=qb/16+1. qb<16 (nc==1): direct O write. Else partial.
//  x in [160,224): local head h=8+y, qb=x-160, window tiles, direct O write.
__global__ __launch_bounds__(256) void attn_pass1(
    const __half* __restrict__ q, const __half* __restrict__ k, const __half* __restrict__ v,
    __half* __restrict__ Ohi, __half* __restrict__ Olo,
    float* __restrict__ partO, float* __restrict__ partML)
{
    __shared__ __align__(16) unsigned char smem[32768];
    char* Qs = (char*)smem;
    char* Ks = (char*)smem + 8192;
    char* Vt = (char*)smem + 16384;
    char* Pl = (char*)smem + 24576;

    int h, qb, kt_lo, kt_hi, pslot = 0;
    bool is_local, direct;
    if (blockIdx.x < 160) {
        h = blockIdx.y;
        is_local = false;
        const int i = 159 - blockIdx.x;          // heaviest chunks dispatch first
        int c;
        if (i < 16)      { qb = i;                c = 0; }
        else if (i < 48) { const int t = i - 16;  qb = 16 + (t >> 1); c = t & 1; }
        else if (i < 96) { const int t = i - 48;  qb = 32 + t / 3;    c = t % 3; }
        else             { const int t = i - 96;  qb = 48 + (t >> 2); c = t & 3; }
        kt_lo = c * 16;
        kt_hi = (kt_lo + 15 < qb) ? kt_lo + 15 : qb;
        direct = (qb < 16);
        pslot  = (h * 48 + (qb - 16)) * 4 + c;   // only used when !direct
    } else {
        h  = 8 + blockIdx.y;
        qb = blockIdx.x - 160;
        is_local = true;
        kt_lo = (qb - 4 > 0) ? qb - 4 : 0;
        kt_hi = qb;
        direct = true;
    }

    const int tid  = threadIdx.x;
    const int w    = tid >> 6;
    const int lane = tid & 63;
    const int lq   = lane & 15;
    const int hi   = lane >> 4;

    const char* qh = (const char*)(q + (size_t)h * S_LEN * HD);
    const char* kh = (const char*)(k + (size_t)h * S_LEN * HD);
    const char* vh = (const char*)(v + (size_t)h * S_LEN * HD);

    #pragma unroll
    for (int e = 0; e < 2; ++e) {
        const int flat = e * 4096 + tid * 16;
        const int row  = flat >> 7;
        const int src  = flat ^ ((row & 7) << 4);
        *(uint4*)(Qs + flat) = *(const uint4*)(qh + (size_t)qb * 8192 + src);
    }
    __syncthreads();

    half8 qf[2];
    #pragma unroll
    for (int ks = 0; ks < 2; ++ks) {
        const int row = w * 16 + lq;
        int byte = row * 128 + hi * 16 + ks * 64;
        byte ^= (row & 7) << 4;
        qf[ks] = *(const half8*)(Qs + byte);
    }

    float m_run = -1e30f, l_run = 0.f;
    f32x4 po[4];
    #pragma unroll
    for (int i = 0; i < 4; ++i) po[i] = (f32x4){0.f, 0.f, 0.f, 0.f};

    const int qg = qb * 64 + w * 16 + lq;
    char* plw = Pl + w * 2048;

    for (int kv = kt_lo; kv <= kt_hi; ++kv) {
        __syncthreads();

        #pragma unroll
        for (int e = 0; e < 2; ++e) {
            const int flat = e * 4096 + tid * 16;
            const int row  = flat >> 7;
            const int src  = flat ^ ((row & 7) << 4);
            *(uint4*)(Ks + flat) = *(const uint4*)(kh + (size_t)kv * 8192 + src);
        }
        {
            const int j0 = (tid & 31) * 2;
            const int d0 = (tid >> 5) * 8;
            ushort8 v0 = *(const ushort8*)(vh + (size_t)(kv * 64 + j0)     * 128 + d0 * 2);
            ushort8 v1 = *(const ushort8*)(vh + (size_t)(kv * 64 + j0 + 1) * 128 + d0 * 2);
            #pragma unroll
            for (int i = 0; i < 8; ++i) {
                const int d = d0 + i;
                int byte = d * 128 + j0 * 2;
                byte ^= (d & 7) << 4;
                *(unsigned int*)(Vt + byte) = (unsigned int)v0[i] | ((unsigned int)v1[i] << 16);
            }
        }
        __syncthreads();

        f32x4 st[4];
        #pragma unroll
        for (int i = 0; i < 4; ++i) st[i] = (f32x4){0.f, 0.f, 0.f, 0.f};
        #pragma unroll
        for (int ks = 0; ks < 2; ++ks) {
            #pragma unroll
            for (int kt = 0; kt < 4; ++kt) {
                const int row = kt * 16 + lq;
                int byte = row * 128 + hi * 16 + ks * 64;
                byte ^= (row & 7) << 4;
                half8 kf = *(const half8*)(Ks + byte);
                st[kt] = mfma16(kf, qf[ks], st[kt]);
            }
        }

        float mx = -1e30f;
        #pragma unroll
        for (int kt = 0; kt < 4; ++kt)
            #pragma unroll
            for (int r = 0; r < 4; ++r) {
                const int kg = kv * 64 + kt * 16 + hi * 4 + r;
                const bool ok = (kg <= qg) && (!is_local || (kg + WIN >= qg));
                const float s = ok ? st[kt][r] : -1e30f;
                st[kt][r] = s;
                mx = fmaxf(mx, s);
            }
        mx = fmaxf(mx, __shfl_xor(mx, 16));
        mx = fmaxf(mx, __shfl_xor(mx, 32));
        const float mnew  = fmaxf(m_run, mx);
        const float scale = __expf(m_run - mnew);
        float lsum = 0.f;
        #pragma unroll
        for (int kt = 0; kt < 4; ++kt)
            #pragma unroll
            for (int r = 0; r < 4; ++r) {
                const float p = __expf(st[kt][r] - mnew);
                st[kt][r] = p;
                lsum += p;
            }
        lsum += __shfl_xor(lsum, 16);
        lsum += __shfl_xor(lsum, 32);
        l_run = l_run * scale + lsum;
        m_run = mnew;
        #pragma unroll
        for (int dt = 0; dt < 4; ++dt)
            #pragma unroll
            for (int r = 0; r < 4; ++r) po[dt][r] *= scale;

        #pragma unroll
        for (int kt = 0; kt < 4; ++kt) {
            int byte = lq * 128 + kt * 32 + hi * 8;
            byte ^= (lq & 7) << 4;
            union { __half2 h2[2]; uint2 u; } pu;
            pu.h2[0] = __floats2half2_rn(st[kt][0], st[kt][1]);
            pu.h2[1] = __floats2half2_rn(st[kt][2], st[kt][3]);
            *(uint2*)(plw + byte) = pu.u;
        }

        #pragma unroll
        for (int ks = 0; ks < 2; ++ks) {
            int pbyte = lq * 128 + ks * 64 + hi * 16;
            pbyte ^= (lq & 7) << 4;
            half8 pf = *(const half8*)(plw + pbyte);
            #pragma unroll
            for (int dt = 0; dt < 4; ++dt) {
                const int drow = dt * 16 + lq;
                int vbyte = drow * 128 + ks * 64 + hi * 16;
                vbyte ^= (drow & 7) << 4;
                half8 vf = *(const half8*)(Vt + vbyte);
                po[dt] = mfma16(vf, pf, po[dt]);
            }
        }
    }

    if (direct) {
        const float linv = 1.0f / l_run;
        __half* oh = Ohi + (size_t)qg * EMB + h * HD;
        __half* ol = Olo + (size_t)qg * EMB + h * HD;
        #pragma unroll
        for (int dt = 0; dt < 4; ++dt)
            #pragma unroll
            for (int r = 0; r < 4; ++r) {
                const float vfull = po[dt][r] * linv;
                const __half vhi = __float2half_rn(vfull);
                oh[dt * 16 + hi * 4 + r] = vhi;
                ol[dt * 16 + hi * 4 + r] = __float2half_rn(vfull - __half2float(vhi));
            }
    } else {
        float* op = partO + (size_t)pslot * 4096 + (w * 16 + lq) * 64;
        #pragma unroll
        for (int dt = 0; dt < 4; ++dt)
            #pragma unroll
            for (int r = 0; r < 4; ++r)
                op[dt * 16 + hi * 4 + r] = po[dt][r];
        if (hi == 0) {
            partML[(size_t)pslot * 128 + (w * 16 + lq) * 2]     = m_run;
            partML[(size_t)pslot * 128 + (w * 16 + lq) * 2 + 1] = l_run;
        }
    }
}

// ---------------- attention pass 2: combine partials (global heads, qb>=16) ----
// grid (48, 8): qb = 16+bx, h = by. 256 thr: row = tid>>2 (64), d0 = (tid&3)*16.
__global__ __launch_bounds__(256) void attn_combine(
    const float* __restrict__ partO, const float* __restrict__ partML,
    __half* __restrict__ Ohi, __half* __restrict__ Olo)
{
    const int qb = 16 + blockIdx.x;
    const int h  = blockIdx.y;
    const int nc = (qb >> 4) + 1;
    const int row = threadIdx.x >> 2;
    const int d0  = (threadIdx.x & 3) * 16;
    const int base_slot = (h * 48 + (qb - 16)) * 4;

    float M = -1e30f, mv[4], lv[4];
    #pragma unroll
    for (int i = 0; i < 4; ++i)
        if (i < nc) {
            mv[i] = partML[(size_t)(base_slot + i) * 128 + row * 2];
            lv[i] = partML[(size_t)(base_slot + i) * 128 + row * 2 + 1];
            M = fmaxf(M, mv[i]);
        }
    float L = 0.f, wgt[4];
    #pragma unroll
    for (int i = 0; i < 4; ++i)
        if (i < nc) {
            wgt[i] = __expf(mv[i] - M);
            L += lv[i] * wgt[i];
        }

    float o[16];
    #pragma unroll
    for (int j = 0; j < 16; ++j) o[j] = 0.f;
    #pragma unroll
    for (int i = 0; i < 4; ++i)
        if (i < nc) {
            const float* src = partO + (size_t)(base_slot + i) * 4096 + row * 64 + d0;
            const float wi = wgt[i];
            #pragma unroll
            for (int j4 = 0; j4 < 4; ++j4) {
                float4 s4 = *(const float4*)(src + j4 * 4);
                o[j4*4+0] = fmaf(wi, s4.x, o[j4*4+0]);
                o[j4*4+1] = fmaf(wi, s4.y, o[j4*4+1]);
                o[j4*4+2] = fmaf(wi, s4.z, o[j4*4+2]);
                o[j4*4+3] = fmaf(wi, s4.w, o[j4*4+3]);
            }
        }
    const float Linv = 1.0f / L;
    ushort8 ph[2], pl[2];
    #pragma unroll
    for (int j = 0; j < 16; ++j) {
        const float vfull = o[j] * Linv;
        const __half vhi = __float2half_rn(vfull);
        ph[j >> 3][j & 7] = __half_as_ushort(vhi);
        pl[j >> 3][j & 7] = __half_as_ushort(__float2half_rn(vfull - __half2float(vhi)));
    }
    const size_t ob = (size_t)(qb * 64 + row) * EMB + h * HD + d0;
    *(ushort8*)((__half*)Ohi + ob)     = ph[0];
    *(ushort8*)((__half*)Ohi + ob + 8) = ph[1];
    *(ushort8*)((__half*)Olo + ob)     = pl[0];
    *(ushort8*)((__half*)Olo + ob + 8) = pl[1];
}

extern "C" void kernel_launch(void* const* d_in, const int* in_sizes, int n_in,
                              void* d_out, int out_size, void* d_ws, size_t ws_size,
                              hipStream_t stream) {
    const float* X  = (const float*)d_in[0];
    const float* Wq = (const float*)d_in[1];
    const float* Wk = (const float*)d_in[2];
    const float* Wv = (const float*)d_in[3];
    const float* Wo = (const float*)d_in[4];
    const float* bo = (const float*)d_in[5];
    float* out = (float*)d_out;

    // workspace (halves). partO/partML alias Wh/Wl, which die after the QKV GEMM.
    __half* ws   = (__half*)d_ws;
    __half* qkvb = ws;                          // [3*16][4096][64]  12,582,912 h
    __half* XOhi = ws + 12582912;               // X-hi then O-hi     4,194,304 h
    __half* XOlo = ws + 16777216;               // X-lo then O-lo     4,194,304 h
    __half* Woh  = ws + 20971520;               //                    1,048,576 h
    __half* Wol  = ws + 22020096;               //                    1,048,576 h
    __half* Wh   = ws + 23068672;               // Wq|Wk|Wv hi        3,145,728 h
    __half* Wl   = ws + 26214400;               //                    3,145,728 h
    float* partO  = (float*)(ws + 23068672);    // 8*48*4 slots * 4096 = 6,291,456 f
    float* partML = partO + 6291456;            // 8*48*4 * 128        =   196,608 f
    // total ws footprint ~ 69 MB

    split_kernel<<<dim3(2048), 256, 0, stream>>>(X, Wq, Wk, Wv, Wo,
                                                 XOhi, XOlo, Wh, Wl, Woh, Wol);
    gemm_split_kernel<<<dim3(32, 24), 256, 0, stream>>>(XOhi, XOlo, Wh, Wl,
                                                        0, qkvb, nullptr, nullptr);
    attn_pass1<<<dim3(224, 8), 256, 0, stream>>>(qkvb, qkvb + 4194304, qkvb + 8388608,
                                                 XOhi, XOlo, partO, partML);
    attn_combine<<<dim3(48, 8), 256, 0, stream>>>(partO, partML, XOhi, XOlo);
    gemm_split_out_kernel<<<dim3(32, 16), 256, 0, stream>>>(XOhi, XOlo, Woh, Wol,
                                                            out, bo);
}

// Round 12
// 252.886 us; speedup vs baseline: 4.8447x; 1.0091x over previous
//
#include <hip/hip_runtime.h>
#include <hip/hip_fp16.h>

#define S_LEN 4096
#define EMB   1024
#define NH    16
#define HD    64
#define GH    8
#define WIN   256

typedef _Float16 half8 __attribute__((ext_vector_type(8)));
typedef float    f32x4 __attribute__((ext_vector_type(4)));
typedef unsigned short ushort8 __attribute__((ext_vector_type(8)));

static __device__ __forceinline__ f32x4 mfma16(half8 a, half8 b, f32x4 c) {
    return __builtin_amdgcn_mfma_f32_16x16x32_f16(a, b, c, 0, 0, 0);
}

#define GLOAD16(g, l) __builtin_amdgcn_global_load_lds( \
    (const __attribute__((address_space(1))) void*)(g), \
    (__attribute__((address_space(3))) void*)(l), 16, 0, 0)

// ---------------- split pass: fp32 -> (hi, lo) fp16 (Wo: hi only) ----------------
__global__ __launch_bounds__(256) void split_kernel(
    const float* __restrict__ X,  const float* __restrict__ Wq, const float* __restrict__ Wk,
    const float* __restrict__ Wv, const float* __restrict__ Wo,
    __half* __restrict__ Xhi, __half* __restrict__ Xlo,
    __half* __restrict__ Wh,  __half* __restrict__ Wl,
    __half* __restrict__ Woh)
{
    const int NT = gridDim.x * blockDim.x;
    for (int i = blockIdx.x * blockDim.x + threadIdx.x; i < 2097152; i += NT) {
        const float* src; __half *dh, *dl; int off;
        if (i < 1048576)      { src = X;  dh = Xhi;           dl = Xlo;           off = i; }
        else if (i < 1310720) { src = Wq; dh = Wh;            dl = Wl;            off = i - 1048576; }
        else if (i < 1572864) { src = Wk; dh = Wh + 1048576;  dl = Wl + 1048576;  off = i - 1310720; }
        else if (i < 1835008) { src = Wv; dh = Wh + 2097152;  dl = Wl + 2097152;  off = i - 1572864; }
        else                  { src = Wo; dh = Woh;           dl = nullptr;       off = i - 1835008; }
        float4 xv = *(const float4*)(src + (size_t)off * 4);
        union { __half h[4]; uint2 u; } ph, pl;
        float xs[4] = {xv.x, xv.y, xv.z, xv.w};
        #pragma unroll
        for (int j = 0; j < 4; ++j) {
            __half hj = __float2half_rn(xs[j]);
            ph.h[j] = hj;
            pl.h[j] = __float2half_rn(xs[j] - __half2float(hj));
        }
        *(uint2*)(dh + (size_t)off * 4) = ph.u;
        if (dl) *(uint2*)(dl + (size_t)off * 4) = pl.u;
    }
}

// ---------------- split-fp16 MFMA GEMM (QKV): C = A * B^T (K = 1024) ----------------
__global__ __launch_bounds__(256) void gemm_split_kernel(
    const __half* __restrict__ Ah_, const __half* __restrict__ Al_,
    const __half* __restrict__ Bh_, const __half* __restrict__ Bl_,
    __half* __restrict__ qkv_out)
{
    __shared__ __align__(16) char lds[65536];
    char* LA_h = lds;
    char* LA_l = lds + 16384;
    char* LB_h = lds + 32768;
    char* LB_l = lds + 49152;

    const int tid  = threadIdx.x;
    const int w    = tid >> 6, lane = tid & 63;
    const int bm   = blockIdx.x * 128, bn = blockIdx.y * 128;
    const int wm0  = (w & 1) * 64, wn0 = (w >> 1) * 64;
    const int lr   = lane & 15;
    const int lk   = lane >> 4;

    const char *gAh[4], *gAl[4], *gBh[4], *gBl[4];
    int ldsoff[4];
    #pragma unroll
    for (int i = 0; i < 4; ++i) {
        const int c = tid + i * 256;
        const int row = c >> 3;
        const int sw  = ((c & 7) ^ (row & 7)) * 16;
        gAh[i] = (const char*)Ah_ + (size_t)(bm + row) * 2048 + sw;
        gAl[i] = (const char*)Al_ + (size_t)(bm + row) * 2048 + sw;
        gBh[i] = (const char*)Bh_ + (size_t)(bn + row) * 2048 + sw;
        gBl[i] = (const char*)Bl_ + (size_t)(bn + row) * 2048 + sw;
        ldsoff[i] = ((tid >> 6) * 64 + i * 256) * 16;
    }

    f32x4 acc[4][4];
    #pragma unroll
    for (int mi = 0; mi < 4; ++mi)
        #pragma unroll
        for (int ni = 0; ni < 4; ++ni) acc[mi][ni] = (f32x4){0.f, 0.f, 0.f, 0.f};

    for (int k0 = 0; k0 < 1024; k0 += 64) {
        __syncthreads();
        const size_t kb = (size_t)k0 * 2;
        #pragma unroll
        for (int i = 0; i < 4; ++i) {
            GLOAD16(gAh[i] + kb, LA_h + ldsoff[i]);
            GLOAD16(gAl[i] + kb, LA_l + ldsoff[i]);
            GLOAD16(gBh[i] + kb, LB_h + ldsoff[i]);
            GLOAD16(gBl[i] + kb, LB_l + ldsoff[i]);
        }
        __syncthreads();

        #pragma unroll
        for (int kh = 0; kh < 2; ++kh) {
            half8 afh[4], afl[4], bfh[4], bfl[4];
            #pragma unroll
            for (int f = 0; f < 4; ++f) {
                const int ar = wm0 + f * 16 + lr;
                const int ab = ar * 128 + ((kh * 64 + lk * 16) ^ ((ar & 7) << 4));
                afh[f] = *(const half8*)(LA_h + ab);
                afl[f] = *(const half8*)(LA_l + ab);
                const int br = wn0 + f * 16 + lr;
                const int bb = br * 128 + ((kh * 64 + lk * 16) ^ ((br & 7) << 4));
                bfh[f] = *(const half8*)(LB_h + bb);
                bfl[f] = *(const half8*)(LB_l + bb);
            }
            #pragma unroll
            for (int mi = 0; mi < 4; ++mi)
                #pragma unroll
                for (int ni = 0; ni < 4; ++ni) {
                    acc[mi][ni] = mfma16(afh[mi], bfh[ni], acc[mi][ni]);
                    acc[mi][ni] = mfma16(afh[mi], bfl[ni], acc[mi][ni]);
                    acc[mi][ni] = mfma16(afl[mi], bfh[ni], acc[mi][ni]);
                }
        }
    }

    #pragma unroll
    for (int ni = 0; ni < 4; ++ni) {
        const int n  = bn + wn0 + ni * 16 + lr;
        const int hg = n >> 6;
        const int d  = n & 63;
        const float alpha = ((n >> 10) == 0) ? 0.125f : 1.0f;
        __half* base = qkv_out + (size_t)hg * S_LEN * HD + d;
        #pragma unroll
        for (int mi = 0; mi < 4; ++mi) {
            const int m = bm + wm0 + mi * 16 + lk * 4;
            #pragma unroll
            for (int r = 0; r < 4; ++r)
                base[(size_t)(m + r) * HD] = __float2half_rn(acc[mi][ni][r] * alpha);
        }
    }
}

// ------- out-proj GEMM, plain fp16: out = O @ Woh^T + bias --------------------
// O is already fp16-rounded (attention output); dropped lo-terms contribute
// ~1e-3 abs vs current absmax 1.56e-2 (measured: fp32 vs split out-proj made
// zero absmax difference). 128x64 tile, LDS 24 KB, 1 MFMA per frag pair.
__global__ __launch_bounds__(256) void gemm_out_f16_kernel(
    const __half* __restrict__ A_, const __half* __restrict__ B_,
    float* __restrict__ fo_out, const float* __restrict__ bias)
{
    __shared__ __align__(16) char lds[24576];
    char* LA = lds;              // [128][64] fp16 = 16 KB
    char* LB = lds + 16384;      // [64][64]  fp16 =  8 KB

    const int tid  = threadIdx.x;
    const int w    = tid >> 6, lane = tid & 63;
    const int bm   = blockIdx.x * 128, bn = blockIdx.y * 64;
    const int wm0  = (w & 1) * 64, wn0 = (w >> 1) * 32;
    const int lr   = lane & 15;
    const int lk   = lane >> 4;

    const char *gA[4], *gB[2];
    int loA[4], loB[2];
    #pragma unroll
    for (int i = 0; i < 4; ++i) {
        const int c = tid + i * 256;
        const int row = c >> 3;
        const int sw  = ((c & 7) ^ (row & 7)) * 16;
        gA[i] = (const char*)A_ + (size_t)(bm + row) * 2048 + sw;
        loA[i] = (w * 64 + i * 256) * 16;
    }
    #pragma unroll
    for (int i = 0; i < 2; ++i) {
        const int c = tid + i * 256;
        const int row = c >> 3;                 // 0..63
        const int sw  = ((c & 7) ^ (row & 7)) * 16;
        gB[i] = (const char*)B_ + (size_t)(bn + row) * 2048 + sw;
        loB[i] = (w * 64 + i * 256) * 16;
    }

    f32x4 acc[4][2];
    #pragma unroll
    for (int mi = 0; mi < 4; ++mi)
        #pragma unroll
        for (int ni = 0; ni < 2; ++ni) acc[mi][ni] = (f32x4){0.f, 0.f, 0.f, 0.f};

    for (int k0 = 0; k0 < 1024; k0 += 64) {
        __syncthreads();
        const size_t kb = (size_t)k0 * 2;
        #pragma unroll
        for (int i = 0; i < 4; ++i) GLOAD16(gA[i] + kb, LA + loA[i]);
        #pragma unroll
        for (int i = 0; i < 2; ++i) GLOAD16(gB[i] + kb, LB + loB[i]);
        __syncthreads();

        #pragma unroll
        for (int kh = 0; kh < 2; ++kh) {
            half8 af[4], bf[2];
            #pragma unroll
            for (int f = 0; f < 4; ++f) {
                const int ar = wm0 + f * 16 + lr;
                af[f] = *(const half8*)(LA + ar * 128 + ((kh * 64 + lk * 16) ^ ((ar & 7) << 4)));
            }
            #pragma unroll
            for (int ni = 0; ni < 2; ++ni) {
                const int br = wn0 + ni * 16 + lr;
                bf[ni] = *(const half8*)(LB + br * 128 + ((kh * 64 + lk * 16) ^ ((br & 7) << 4)));
            }
            #pragma unroll
            for (int mi = 0; mi < 4; ++mi)
                #pragma unroll
                for (int ni = 0; ni < 2; ++ni)
                    acc[mi][ni] = mfma16(af[mi], bf[ni], acc[mi][ni]);
        }
    }

    #pragma unroll
    for (int ni = 0; ni < 2; ++ni) {
        const int n = bn + wn0 + ni * 16 + lr;
        const float bv = bias[n];
        #pragma unroll
        for (int mi = 0; mi < 4; ++mi) {
            const int m = bm + wm0 + mi * 16 + lk * 4;
            #pragma unroll
            for (int r = 0; r < 4; ++r)
                fo_out[(size_t)(m + r) * EMB + n] = acc[mi][ni][r] + bv;
        }
    }
}

// ---------------- attention pass 1: split-KV flash, fp16 MFMA ----------------
// grid (224, 8), 256 thr = 4 waves. O written as fp16 (hi only).
__global__ __launch_bounds__(256) void attn_pass1(
    const __half* __restrict__ q, const __half* __restrict__ k, const __half* __restrict__ v,
    __half* __restrict__ Oh,
    float* __restrict__ partO, float* __restrict__ partML)
{
    __shared__ __align__(16) unsigned char smem[32768];
    char* Qs = (char*)smem;
    char* Ks = (char*)smem + 8192;
    char* Vt = (char*)smem + 16384;
    char* Pl = (char*)smem + 24576;

    int h, qb, kt_lo, kt_hi, pslot = 0;
    bool is_local, direct;
    if (blockIdx.x < 160) {
        h = blockIdx.y;
        is_local = false;
        const int i = 159 - blockIdx.x;          // heaviest chunks dispatch first
        int c;
        if (i < 16)      { qb = i;                c = 0; }
        else if (i < 48) { const int t = i - 16;  qb = 16 + (t >> 1); c = t & 1; }
        else if (i < 96) { const int t = i - 48;  qb = 32 + t / 3;    c = t % 3; }
        else             { const int t = i - 96;  qb = 48 + (t >> 2); c = t & 3; }
        kt_lo = c * 16;
        kt_hi = (kt_lo + 15 < qb) ? kt_lo + 15 : qb;
        direct = (qb < 16);
        pslot  = (h * 48 + (qb - 16)) * 4 + c;   // only used when !direct
    } else {
        h  = 8 + blockIdx.y;
        qb = blockIdx.x - 160;
        is_local = true;
        kt_lo = (qb - 4 > 0) ? qb - 4 : 0;
        kt_hi = qb;
        direct = true;
    }

    const int tid  = threadIdx.x;
    const int w    = tid >> 6;
    const int lane = tid & 63;
    const int lq   = lane & 15;
    const int hi   = lane >> 4;

    const char* qh = (const char*)(q + (size_t)h * S_LEN * HD);
    const char* kh = (const char*)(k + (size_t)h * S_LEN * HD);
    const char* vh = (const char*)(v + (size_t)h * S_LEN * HD);

    #pragma unroll
    for (int e = 0; e < 2; ++e) {
        const int flat = e * 4096 + tid * 16;
        const int row  = flat >> 7;
        const int src  = flat ^ ((row & 7) << 4);
        *(uint4*)(Qs + flat) = *(const uint4*)(qh + (size_t)qb * 8192 + src);
    }
    __syncthreads();

    half8 qf[2];
    #pragma unroll
    for (int ks = 0; ks < 2; ++ks) {
        const int row = w * 16 + lq;
        int byte = row * 128 + hi * 16 + ks * 64;
        byte ^= (row & 7) << 4;
        qf[ks] = *(const half8*)(Qs + byte);
    }

    float m_run = -1e30f, l_run = 0.f;
    f32x4 po[4];
    #pragma unroll
    for (int i = 0; i < 4; ++i) po[i] = (f32x4){0.f, 0.f, 0.f, 0.f};

    const int qg = qb * 64 + w * 16 + lq;
    char* plw = Pl + w * 2048;

    for (int kv = kt_lo; kv <= kt_hi; ++kv) {
        __syncthreads();

        #pragma unroll
        for (int e = 0; e < 2; ++e) {
            const int flat = e * 4096 + tid * 16;
            const int row  = flat >> 7;
            const int src  = flat ^ ((row & 7) << 4);
            *(uint4*)(Ks + flat) = *(const uint4*)(kh + (size_t)kv * 8192 + src);
        }
        {
            const int j0 = (tid & 31) * 2;
            const int d0 = (tid >> 5) * 8;
            ushort8 v0 = *(const ushort8*)(vh + (size_t)(kv * 64 + j0)     * 128 + d0 * 2);
            ushort8 v1 = *(const ushort8*)(vh + (size_t)(kv * 64 + j0 + 1) * 128 + d0 * 2);
            #pragma unroll
            for (int i = 0; i < 8; ++i) {
                const int d = d0 + i;
                int byte = d * 128 + j0 * 2;
                byte ^= (d & 7) << 4;
                *(unsigned int*)(Vt + byte) = (unsigned int)v0[i] | ((unsigned int)v1[i] << 16);
            }
        }
        __syncthreads();

        f32x4 st[4];
        #pragma unroll
        for (int i = 0; i < 4; ++i) st[i] = (f32x4){0.f, 0.f, 0.f, 0.f};
        #pragma unroll
        for (int ks = 0; ks < 2; ++ks) {
            #pragma unroll
            for (int kt = 0; kt < 4; ++kt) {
                const int row = kt * 16 + lq;
                int byte = row * 128 + hi * 16 + ks * 64;
                byte ^= (row & 7) << 4;
                half8 kf = *(const half8*)(Ks + byte);
                st[kt] = mfma16(kf, qf[ks], st[kt]);
            }
        }

        float mx = -1e30f;
        #pragma unroll
        for (int kt = 0; kt < 4; ++kt)
            #pragma unroll
            for (int r = 0; r < 4; ++r) {
                const int kg = kv * 64 + kt * 16 + hi * 4 + r;
                const bool ok = (kg <= qg) && (!is_local || (kg + WIN >= qg));
                const float s = ok ? st[kt][r] : -1e30f;
                st[kt][r] = s;
                mx = fmaxf(mx, s);
            }
        mx = fmaxf(mx, __shfl_xor(mx, 16));
        mx = fmaxf(mx, __shfl_xor(mx, 32));
        const float mnew  = fmaxf(m_run, mx);
        const float scale = __expf(m_run - mnew);
        float lsum = 0.f;
        #pragma unroll
        for (int kt = 0; kt < 4; ++kt)
            #pragma unroll
            for (int r = 0; r < 4; ++r) {
                const float p = __expf(st[kt][r] - mnew);
                st[kt][r] = p;
                lsum += p;
            }
        lsum += __shfl_xor(lsum, 16);
        lsum += __shfl_xor(lsum, 32);
        l_run = l_run * scale + lsum;
        m_run = mnew;
        #pragma unroll
        for (int dt = 0; dt < 4; ++dt)
            #pragma unroll
            for (int r = 0; r < 4; ++r) po[dt][r] *= scale;

        #pragma unroll
        for (int kt = 0; kt < 4; ++kt) {
            int byte = lq * 128 + kt * 32 + hi * 8;
            byte ^= (lq & 7) << 4;
            union { __half2 h2[2]; uint2 u; } pu;
            pu.h2[0] = __floats2half2_rn(st[kt][0], st[kt][1]);
            pu.h2[1] = __floats2half2_rn(st[kt][2], st[kt][3]);
            *(uint2*)(plw + byte) = pu.u;
        }

        #pragma unroll
        for (int ks = 0; ks < 2; ++ks) {
            int pbyte = lq * 128 + ks * 64 + hi * 16;
            pbyte ^= (lq & 7) << 4;
            half8 pf = *(const half8*)(plw + pbyte);
            #pragma unroll
            for (int dt = 0; dt < 4; ++dt) {
                const int drow = dt * 16 + lq;
                int vbyte = drow * 128 + ks * 64 + hi * 16;
                vbyte ^= (drow & 7) << 4;
                half8 vf = *(const half8*)(Vt + vbyte);
                po[dt] = mfma16(vf, pf, po[dt]);
            }
        }
    }

    if (direct) {
        const float linv = 1.0f / l_run;
        __half* oh = Oh + (size_t)qg * EMB + h * HD;
        #pragma unroll
        for (int dt = 0; dt < 4; ++dt)
            #pragma unroll
            for (int r = 0; r < 4; ++r)
                oh[dt * 16 + hi * 4 + r] = __float2half_rn(po[dt][r] * linv);
    } else {
        float* op = partO + (size_t)pslot * 4096 + (w * 16 + lq) * 64;
        #pragma unroll
        for (int dt = 0; dt < 4; ++dt)
            #pragma unroll
            for (int r = 0; r < 4; ++r)
                op[dt * 16 + hi * 4 + r] = po[dt][r];
        if (hi == 0) {
            partML[(size_t)pslot * 128 + (w * 16 + lq) * 2]     = m_run;
            partML[(size_t)pslot * 128 + (w * 16 + lq) * 2 + 1] = l_run;
        }
    }
}

// ---------------- attention pass 2: combine partials (global heads, qb>=16) ----
__global__ __launch_bounds__(256) void attn_combine(
    const float* __restrict__ partO, const float* __restrict__ partML,
    __half* __restrict__ Oh)
{
    const int qb = 16 + blockIdx.x;
    const int h  = blockIdx.y;
    const int nc = (qb >> 4) + 1;
    const int row = threadIdx.x >> 2;
    const int d0  = (threadIdx.x & 3) * 16;
    const int base_slot = (h * 48 + (qb - 16)) * 4;

    float M = -1e30f, mv[4], lv[4];
    #pragma unroll
    for (int i = 0; i < 4; ++i)
        if (i < nc) {
            mv[i] = partML[(size_t)(base_slot + i) * 128 + row * 2];
            lv[i] = partML[(size_t)(base_slot + i) * 128 + row * 2 + 1];
            M = fmaxf(M, mv[i]);
        }
    float L = 0.f, wgt[4];
    #pragma unroll
    for (int i = 0; i < 4; ++i)
        if (i < nc) {
            wgt[i] = __expf(mv[i] - M);
            L += lv[i] * wgt[i];
        }

    float o[16];
    #pragma unroll
    for (int j = 0; j < 16; ++j) o[j] = 0.f;
    #pragma unroll
    for (int i = 0; i < 4; ++i)
        if (i < nc) {
            const float* src = partO + (size_t)(base_slot + i) * 4096 + row * 64 + d0;
            const float wi = wgt[i];
            #pragma unroll
            for (int j4 = 0; j4 < 4; ++j4) {
                float4 s4 = *(const float4*)(src + j4 * 4);
                o[j4*4+0] = fmaf(wi, s4.x, o[j4*4+0]);
                o[j4*4+1] = fmaf(wi, s4.y, o[j4*4+1]);
                o[j4*4+2] = fmaf(wi, s4.z, o[j4*4+2]);
                o[j4*4+3] = fmaf(wi, s4.w, o[j4*4+3]);
            }
        }
    const float Linv = 1.0f / L;
    ushort8 ph[2];
    #pragma unroll
    for (int j = 0; j < 16; ++j)
        ph[j >> 3][j & 7] = __half_as_ushort(__float2half_rn(o[j] * Linv));
    const size_t ob = (size_t)(qb * 64 + row) * EMB + h * HD + d0;
    *(ushort8*)((__half*)Oh + ob)     = ph[0];
    *(ushort8*)((__half*)Oh + ob + 8) = ph[1];
}

extern "C" void kernel_launch(void* const* d_in, const int* in_sizes, int n_in,
                              void* d_out, int out_size, void* d_ws, size_t ws_size,
                              hipStream_t stream) {
    const float* X  = (const float*)d_in[0];
    const float* Wq = (const float*)d_in[1];
    const float* Wk = (const float*)d_in[2];
    const float* Wv = (const float*)d_in[3];
    const float* Wo = (const float*)d_in[4];
    const float* bo = (const float*)d_in[5];
    float* out = (float*)d_out;

    // workspace (halves). partO/partML alias Wh/Wl, which die after the QKV GEMM.
    __half* ws   = (__half*)d_ws;
    __half* qkvb = ws;                          // [3*16][4096][64]  12,582,912 h
    __half* XOhi = ws + 12582912;               // X-hi then O        4,194,304 h
    __half* XOlo = ws + 16777216;               // X-lo               4,194,304 h
    __half* Woh  = ws + 20971520;               //                    1,048,576 h
    // ws + 22020096 .. 23068672: unused (was Wol)
    __half* Wh   = ws + 23068672;               // Wq|Wk|Wv hi        3,145,728 h
    __half* Wl   = ws + 26214400;               //                    3,145,728 h
    float* partO  = (float*)(ws + 23068672);    // 8*48*4 slots * 4096 = 6,291,456 f
    float* partML = partO + 6291456;            // 8*48*4 * 128        =   196,608 f
    // total ws footprint ~ 69 MB (unchanged high-water)

    split_kernel<<<dim3(2048), 256, 0, stream>>>(X, Wq, Wk, Wv, Wo,
                                                 XOhi, XOlo, Wh, Wl, Woh);
    gemm_split_kernel<<<dim3(32, 24), 256, 0, stream>>>(XOhi, XOlo, Wh, Wl, qkvb);
    attn_pass1<<<dim3(224, 8), 256, 0, stream>>>(qkvb, qkvb + 4194304, qkvb + 8388608,
                                                 XOhi, partO, partML);
    attn_combine<<<dim3(48, 8), 256, 0, stream>>>(partO, partML, XOhi);
    gemm_out_f16_kernel<<<dim3(32, 16), 256, 0, stream>>>(XOhi, Woh, out, bo);
}